// Round 1
// baseline (2463.397 us; speedup 1.0000x reference)
//
#include <hip/hip_runtime.h>
#include <math.h>

// ---------------- constants ----------------
constexpr int Bv = 2, Nv = 2048, NCv = 256;
constexpr int CSv = 384, CCONDv = 256;
constexpr int CHv = 16, Hv = 12, PQKv = 4, PVv = 8;
constexpr int BQv = 32, BKv = 128, NBLKv = 64;
constexpr int HC = Hv * CHv;               // 192
constexpr int QPD = Hv * PQKv * 3;         // 144
constexpr int KVPD = Hv * (PQKv + PVv) * 3;// 432
constexpr int FEAT = 960;                  // H*CONCAT
constexpr float S1 = 0.14433756729740643f; // sqrt(1/48)
constexpr float S2 = 0.5773502691896258f;  // sqrt(1/3)
constexpr float HWS = 0.13608276348795434f;// sqrt(1/54)

// ---------------- helpers ----------------
__device__ __forceinline__ float blockReduceSum(float v, volatile float* red, int t, int nthr) {
    #pragma unroll
    for (int off = 32; off > 0; off >>= 1) v += __shfl_down(v, off, 64);
    int wid = t >> 6, lane = t & 63, nw = nthr >> 6;
    __syncthreads();
    if (lane == 0) red[wid] = v;
    __syncthreads();
    float r = 0.f;
    for (int w = 0; w < nw; ++w) r += red[w];
    return r;
}

// ---------------- K1: LN(cond) + gate/bias projections ----------------
__global__ __launch_bounds__(256) void k_cond(const float* __restrict__ cond,
                                              const float* __restrict__ lnw,
                                              const float* __restrict__ Wg,
                                              const float* __restrict__ bg,
                                              const float* __restrict__ Wnb,
                                              float* __restrict__ gate_full,
                                              float* __restrict__ bias_full) {
    __shared__ float cn[CCONDv];
    __shared__ float red[4];
    int row = blockIdx.x;          // b*NC + r
    int t = threadIdx.x;           // 256
    float c = cond[row * CCONDv + t];
    float mu = blockReduceSum(c, red, t, 256) * (1.f / CCONDv);
    float d = c - mu;
    float var = blockReduceSum(d * d, red, t, 256) * (1.f / CCONDv);
    cn[t] = d * rsqrtf(var + 1e-5f) * lnw[t];
    __syncthreads();
    for (int c0 = t; c0 < CSv; c0 += 256) {
        const float* w1 = Wg + (size_t)c0 * CCONDv;
        const float* w2 = Wnb + (size_t)c0 * CCONDv;
        float g = 0.f, bb = 0.f;
        for (int i = 0; i < CCONDv; ++i) { g += w1[i] * cn[i]; bb += w2[i] * cn[i]; }
        gate_full[row * CSv + c0] = g + bg[c0];
        bias_full[row * CSv + c0] = bb;
    }
}

// ---------------- K2: LN(s) + gather gate/bias -> s2 ----------------
__global__ __launch_bounds__(128) void k_s2(const float* __restrict__ s,
                                            const float* __restrict__ gate_full,
                                            const float* __restrict__ bias_full,
                                            const int* __restrict__ cidx,
                                            const float* __restrict__ smask,
                                            float* __restrict__ s2) {
    __shared__ float red[4];
    int row = blockIdx.x;          // b*N + n
    int t = threadIdx.x;           // 128
    const float* sr = s + (size_t)row * CSv;
    float x0 = sr[t], x1 = sr[t + 128], x2 = sr[t + 256];
    float mu = blockReduceSum(x0 + x1 + x2, red, t, 128) * (1.f / CSv);
    float d0 = x0 - mu, d1 = x1 - mu, d2 = x2 - mu;
    float var = blockReduceSum(d0 * d0 + d1 * d1 + d2 * d2, red, t, 128) * (1.f / CSv);
    float rs = rsqrtf(var + 1e-5f);
    int b = row / Nv;
    int ci = cidx[row];
    float m = smask[row];
    const float* gf = gate_full + (size_t)(b * NCv + ci) * CSv;
    const float* bf = bias_full + (size_t)(b * NCv + ci) * CSv;
    float dd[3] = {d0, d1, d2};
    #pragma unroll
    for (int j = 0; j < 3; ++j) {
        int cc = t + j * 128;
        float sn = dd[j] * rs;
        float g = gf[cc] * m, bi = bf[cc] * m;
        s2[(size_t)row * CSv + cc] = sn * (1.f / (1.f + expf(-g))) + bi;
    }
}

// ---------------- K3: per-row projections q/k/v/qpts/kpts/vpts/qsq/ksq ----------------
__global__ __launch_bounds__(256) void k_proj(const float* __restrict__ s2,
                                              const float* __restrict__ Wq,
                                              const float* __restrict__ Wk,
                                              const float* __restrict__ Wv,
                                              const float* __restrict__ Wqp,
                                              const float* __restrict__ Wkvp,
                                              const float* __restrict__ rots,
                                              const float* __restrict__ trans,
                                              float* __restrict__ qc, float* __restrict__ kc,
                                              float* __restrict__ vc,
                                              float* __restrict__ qpts, float* __restrict__ kpts,
                                              float* __restrict__ vpts,
                                              float* __restrict__ qsq, float* __restrict__ ksq) {
    __shared__ float s2t[8 * 385];
    __shared__ float outbuf[8 * 1156];
    __shared__ float Rl[8][9];
    __shared__ float trl[8][3];
    __shared__ float sqacc[8 * 24];
    int t = threadIdx.x;           // 256
    int n0 = blockIdx.x * 8;       // global row base (b*N+n)

    for (int idx = t; idx < 8 * CSv; idx += 256) {
        int r = idx / CSv, c = idx % CSv;
        s2t[r * 385 + c] = s2[(size_t)(n0 + r) * CSv + c];
    }
    for (int idx = t; idx < 72; idx += 256) Rl[idx / 9][idx % 9] = rots[(size_t)(n0 + idx / 9) * 9 + idx % 9];
    for (int idx = t; idx < 24; idx += 256) trl[idx / 3][idx % 3] = trans[(size_t)(n0 + idx / 3) * 3 + idx % 3];
    for (int idx = t; idx < 8 * 24; idx += 256) sqacc[idx] = 0.f;
    __syncthreads();

    // 1152 outputs per row
    for (int c = t; c < 1152; c += 256) {
        const float* w;
        if (c < 192) w = Wq + (size_t)c * CSv;
        else if (c < 384) w = Wk + (size_t)(c - 192) * CSv;
        else if (c < 576) w = Wv + (size_t)(c - 384) * CSv;
        else if (c < 720) w = Wqp + (size_t)(c - 576) * CSv;
        else w = Wkvp + (size_t)(c - 720) * CSv;
        float acc[8] = {0, 0, 0, 0, 0, 0, 0, 0};
        for (int i = 0; i < CSv; ++i) {
            float wv = w[i];
            #pragma unroll
            for (int r = 0; r < 8; ++r) acc[r] += wv * s2t[r * 385 + i];
        }
        #pragma unroll
        for (int r = 0; r < 8; ++r) outbuf[r * 1156 + c] = acc[r];
    }
    __syncthreads();

    // q/k/v copy out
    for (int idx = t; idx < 8 * 576; idx += 256) {
        int r = idx / 576, c = idx % 576;
        float val = outbuf[r * 1156 + c];
        size_t n = n0 + r;
        if (c < 192) qc[n * HC + c] = val;
        else if (c < 384) kc[n * HC + (c - 192)] = val;
        else vc[n * HC + (c - 384)] = val;
    }
    // q points: 48 per row
    for (int idx = t; idx < 8 * 48; idx += 256) {
        int r = idx / 48, p = idx % 48;
        float x = outbuf[r * 1156 + 576 + p * 3 + 0];
        float y = outbuf[r * 1156 + 576 + p * 3 + 1];
        float z = outbuf[r * 1156 + 576 + p * 3 + 2];
        const float* R = Rl[r];
        float ox = R[0] * x + R[1] * y + R[2] * z + trl[r][0];
        float oy = R[3] * x + R[4] * y + R[5] * z + trl[r][1];
        float oz = R[6] * x + R[7] * y + R[8] * z + trl[r][2];
        size_t n = n0 + r;
        qpts[n * QPD + p * 3 + 0] = ox;
        qpts[n * QPD + p * 3 + 1] = oy;
        qpts[n * QPD + p * 3 + 2] = oz;
        atomicAdd(&sqacc[r * 24 + p / PQKv], ox * ox + oy * oy + oz * oz);
    }
    // kv points: 144 per row
    for (int idx = t; idx < 8 * 144; idx += 256) {
        int r = idx / 144, p = idx % 144;
        float x = outbuf[r * 1156 + 720 + p * 3 + 0];
        float y = outbuf[r * 1156 + 720 + p * 3 + 1];
        float z = outbuf[r * 1156 + 720 + p * 3 + 2];
        const float* R = Rl[r];
        float ox = R[0] * x + R[1] * y + R[2] * z + trl[r][0];
        float oy = R[3] * x + R[4] * y + R[5] * z + trl[r][1];
        float oz = R[6] * x + R[7] * y + R[8] * z + trl[r][2];
        size_t n = n0 + r;
        int h = p / 12, pp = p % 12;
        if (pp < PQKv) {
            kpts[n * QPD + (h * PQKv + pp) * 3 + 0] = ox;
            kpts[n * QPD + (h * PQKv + pp) * 3 + 1] = oy;
            kpts[n * QPD + (h * PQKv + pp) * 3 + 2] = oz;
            atomicAdd(&sqacc[r * 24 + 12 + h], ox * ox + oy * oy + oz * oz);
        } else {
            vpts[n * (Hv * PVv * 3) + (h * PVv + pp - PQKv) * 3 + 0] = ox;
            vpts[n * (Hv * PVv * 3) + (h * PVv + pp - PQKv) * 3 + 1] = oy;
            vpts[n * (Hv * PVv * 3) + (h * PVv + pp - PQKv) * 3 + 2] = oz;
        }
    }
    __syncthreads();
    for (int idx = t; idx < 8 * 12; idx += 256) {
        int r = idx / 12, h = idx % 12;
        size_t n = n0 + r;
        qsq[n * Hv + h] = sqacc[r * 24 + h];
        ksq[n * Hv + h] = sqacc[r * 24 + 12 + h];
    }
}

// ---------------- K4: LN(z) + Wb/Wdz projections ----------------
__global__ __launch_bounds__(128) void k_zproj(const float* __restrict__ z,
                                               const float* __restrict__ lnw,
                                               const float* __restrict__ lnb,
                                               const float* __restrict__ Wb,
                                               const float* __restrict__ Wdz,
                                               float* __restrict__ bbias,
                                               float* __restrict__ pairz) {
    __shared__ float znl[128];
    __shared__ float red[4];
    __shared__ float partial[88];
    int row = blockIdx.x;
    int t = threadIdx.x;           // 128
    float zv = z[(size_t)row * 128 + t];
    float mu = blockReduceSum(zv, red, t, 128) * (1.f / 128.f);
    float d = zv - mu;
    float var = blockReduceSum(d * d, red, t, 128) * (1.f / 128.f);
    znl[t] = d * rsqrtf(var + 1e-5f) * lnw[t] + lnb[t];
    __syncthreads();
    if (t < 88) {
        int c = t % 44, half = t / 44;
        const float* w = (c < 12) ? (Wb + (size_t)c * 128) : (Wdz + (size_t)(c - 12) * 128);
        float acc = 0.f;
        int i0 = half * 64;
        #pragma unroll 8
        for (int i = 0; i < 64; ++i) acc += znl[i0 + i] * w[i0 + i];
        partial[t] = acc;
    }
    __syncthreads();
    if (t < 44) {
        float acc = partial[t] + partial[t + 44];
        if (t < 12) bbias[(size_t)row * 12 + t] = acc;
        else pairz[(size_t)row * 32 + (t - 12)] = acc;
    }
}

// ---------------- K5: attention per (b, blk, q) ----------------
__global__ __launch_bounds__(128) void k_attn(const float* __restrict__ qc,
                                              const float* __restrict__ kc,
                                              const float* __restrict__ vc,
                                              const float* __restrict__ qpts,
                                              const float* __restrict__ kpts,
                                              const float* __restrict__ vpts,
                                              const float* __restrict__ qsq,
                                              const float* __restrict__ ksq,
                                              const float* __restrict__ bbias,
                                              const float* __restrict__ pairz,
                                              const float* __restrict__ rots,
                                              const float* __restrict__ trans,
                                              const float* __restrict__ smask,
                                              const float* __restrict__ head_w,
                                              float* __restrict__ feats) {
    __shared__ float qv[HC];
    __shared__ float qp_l[QPD];
    __shared__ float qsq_l[Hv];
    __shared__ float hwl[Hv];
    __shared__ float Rl[9];
    __shared__ float trl[3];
    __shared__ float Amat[Hv * BKv];
    __shared__ int nkg_l[BKv];
    __shared__ float featbuf[FEAT];
    __shared__ float optraw[Hv * PVv * 3];

    int t = threadIdx.x;           // 128
    int b = blockIdx.x / (NBLKv * BQv);
    int rem = blockIdx.x % (NBLKv * BQv);
    int blk = rem / BQv, qq = rem % BQv;
    int nq = blk * BQv + qq;
    int nqg = b * Nv + nq;
    int zbase = ((b * NBLKv + blk) * BQv + qq) * BKv;

    for (int i = t; i < HC; i += 128) qv[i] = qc[(size_t)nqg * HC + i];
    for (int i = t; i < QPD; i += 128) qp_l[i] = qpts[(size_t)nqg * QPD + i];
    if (t < Hv) {
        qsq_l[t] = qsq[(size_t)nqg * Hv + t];
        hwl[t] = log1pf(expf(head_w[t])) * HWS;
    }
    if (t < 9) Rl[t] = rots[(size_t)nqg * 9 + t];
    if (t < 3) trl[t] = trans[(size_t)nqg * 3 + t];
    float qm = smask[nqg];
    __syncthreads();

    // phase 1: logits
    {
        int kk = t;
        int nkrel = blk * BQv + kk - 48;
        bool valid = (nkrel >= 0) && (nkrel < Nv);
        int nkg = valid ? (b * Nv + nkrel) : -1;
        nkg_l[kk] = nkg;
        float km = valid ? smask[nkg] : 0.f;
        float Mterm = 1e5f * (qm * km - 1.f);
        for (int h = 0; h < Hv; ++h) {
            float dqk = 0.f, dpt = 0.f, ksqv = 0.f;
            if (valid) {
                const float* kr = kc + (size_t)nkg * HC + h * CHv;
                #pragma unroll
                for (int c = 0; c < CHv; ++c) dqk += qv[h * CHv + c] * kr[c];
                const float* kp = kpts + (size_t)nkg * QPD + h * 12;
                #pragma unroll
                for (int e = 0; e < 12; ++e) dpt += qp_l[h * 12 + e] * kp[e];
                ksqv = ksq[(size_t)nkg * Hv + h];
            }
            float hw = hwl[h];
            float logit = S1 * dqk + S2 * bbias[(size_t)(zbase + kk) * 12 + h]
                        + hw * dpt - 0.5f * hw * (qsq_l[h] + ksqv) + Mterm;
            Amat[h * BKv + kk] = logit;
        }
    }
    __syncthreads();

    // phase 2: softmax over k (each wave handles 6 heads, 128 vals = 2/lane)
    {
        int w = t >> 6, lane = t & 63;
        for (int h = w * 6; h < w * 6 + 6; ++h) {
            float v0 = Amat[h * BKv + lane], v1 = Amat[h * BKv + 64 + lane];
            float m = fmaxf(v0, v1);
            #pragma unroll
            for (int off = 32; off > 0; off >>= 1) m = fmaxf(m, __shfl_xor(m, off, 64));
            float e0 = expf(v0 - m), e1 = expf(v1 - m);
            float ssum = e0 + e1;
            #pragma unroll
            for (int off = 32; off > 0; off >>= 1) ssum += __shfl_xor(ssum, off, 64);
            float inv = 1.f / ssum;
            Amat[h * BKv + lane] = e0 * inv;
            Amat[h * BKv + 64 + lane] = e1 * inv;
        }
    }
    __syncthreads();

    // phase 3: weighted sums (864 outputs)
    for (int o = t; o < 864; o += 128) {
        float acc = 0.f;
        if (o < 192) {
            int h = o >> 4, c = o & 15;
            for (int k = 0; k < BKv; ++k) {
                int g = nkg_l[k];
                if (g >= 0) acc += Amat[h * BKv + k] * vc[(size_t)g * HC + h * CHv + c];
            }
            featbuf[o] = acc;
        } else if (o < 480) {
            int po = o - 192;
            int h = po / 24, r2 = po % 24;
            for (int k = 0; k < BKv; ++k) {
                int g = nkg_l[k];
                if (g >= 0) acc += Amat[h * BKv + k] * vpts[(size_t)g * (Hv * PVv * 3) + h * 24 + r2];
            }
            optraw[po] = acc;
        } else {
            int po = o - 480;
            int h = po >> 5, c = po & 31;
            for (int k = 0; k < BKv; ++k)
                acc += Amat[h * BKv + k] * pairz[(size_t)(zbase + k) * 32 + c];
            featbuf[576 + po] = acc;
        }
    }
    __syncthreads();

    // phase 4: rotate o_pt back to local frame + norms
    if (t < Hv * PVv) {
        float x = optraw[t * 3 + 0] - trl[0];
        float y = optraw[t * 3 + 1] - trl[1];
        float z = optraw[t * 3 + 2] - trl[2];
        float lx = Rl[0] * x + Rl[3] * y + Rl[6] * z;
        float ly = Rl[1] * x + Rl[4] * y + Rl[7] * z;
        float lz = Rl[2] * x + Rl[5] * y + Rl[8] * z;
        featbuf[192 + t * 3 + 0] = lx;
        featbuf[192 + t * 3 + 1] = ly;
        featbuf[192 + t * 3 + 2] = lz;
        featbuf[480 + t] = sqrtf(lx * lx + ly * ly + lz * lz + 1e-8f);
    }
    __syncthreads();
    for (int c = t; c < FEAT; c += 128) feats[(size_t)nqg * FEAT + c] = featbuf[c];
}

// ---------------- K6: out = feats @ Wout^T (4096x960x384) ----------------
__global__ __launch_bounds__(256) void k_out(const float* __restrict__ A,
                                             const float* __restrict__ Wo,
                                             float* __restrict__ C) {
    __shared__ float As[32][65];
    __shared__ float Bs[32][65];
    int t = threadIdx.x;
    int m0 = blockIdx.x * 64;
    int c0 = blockIdx.y * 64;
    int tx = t & 15, ty = t >> 4;
    int lr = t >> 2, lk = (t & 3) * 8;
    float acc[4][4] = {};
    for (int k0 = 0; k0 < FEAT; k0 += 32) {
        const float4* ap = (const float4*)(A + (size_t)(m0 + lr) * FEAT + k0 + lk);
        const float4* bp = (const float4*)(Wo + (size_t)(c0 + lr) * FEAT + k0 + lk);
        float4 a0 = ap[0], a1 = ap[1];
        float4 b0 = bp[0], b1 = bp[1];
        As[lk + 0][lr] = a0.x; As[lk + 1][lr] = a0.y; As[lk + 2][lr] = a0.z; As[lk + 3][lr] = a0.w;
        As[lk + 4][lr] = a1.x; As[lk + 5][lr] = a1.y; As[lk + 6][lr] = a1.z; As[lk + 7][lr] = a1.w;
        Bs[lk + 0][lr] = b0.x; Bs[lk + 1][lr] = b0.y; Bs[lk + 2][lr] = b0.z; Bs[lk + 3][lr] = b0.w;
        Bs[lk + 4][lr] = b1.x; Bs[lk + 5][lr] = b1.y; Bs[lk + 6][lr] = b1.z; Bs[lk + 7][lr] = b1.w;
        __syncthreads();
        #pragma unroll
        for (int kk = 0; kk < 32; ++kk) {
            float a4[4], b4[4];
            #pragma unroll
            for (int i = 0; i < 4; ++i) a4[i] = As[kk][ty * 4 + i];
            #pragma unroll
            for (int j = 0; j < 4; ++j) b4[j] = Bs[kk][tx * 4 + j];
            #pragma unroll
            for (int i = 0; i < 4; ++i)
                #pragma unroll
                for (int j = 0; j < 4; ++j) acc[i][j] += a4[i] * b4[j];
        }
        __syncthreads();
    }
    #pragma unroll
    for (int i = 0; i < 4; ++i)
        #pragma unroll
        for (int j = 0; j < 4; ++j)
            C[(size_t)(m0 + ty * 4 + i) * CSv + c0 + tx * 4 + j] = acc[i][j];
}

// ---------------- launch ----------------
extern "C" void kernel_launch(void* const* d_in, const int* in_sizes, int n_in,
                              void* d_out, int out_size, void* d_ws, size_t ws_size,
                              hipStream_t stream) {
    const float* s          = (const float*)d_in[0];
    const float* cond       = (const float*)d_in[1];
    const float* z          = (const float*)d_in[2];
    const float* trans      = (const float*)d_in[3];
    const float* rots       = (const float*)d_in[4];
    const float* smask      = (const float*)d_in[5];
    const int*   cidx       = (const int*)d_in[6];
    const float* ln_cond_w  = (const float*)d_in[7];
    const float* lin_cond_W = (const float*)d_in[8];
    const float* lin_cond_b = (const float*)d_in[9];
    const float* lin_cond_nb_W = (const float*)d_in[10];
    const float* ln_z_w     = (const float*)d_in[11];
    const float* ln_z_b     = (const float*)d_in[12];
    const float* Wq         = (const float*)d_in[13];
    const float* Wk         = (const float*)d_in[14];
    const float* Wv         = (const float*)d_in[15];
    const float* Wqp        = (const float*)d_in[16];
    const float* Wkvp       = (const float*)d_in[17];
    const float* Wb         = (const float*)d_in[18];
    const float* Wdz        = (const float*)d_in[19];
    const float* head_w     = (const float*)d_in[20];
    const float* Wout       = (const float*)d_in[21];
    float* out = (float*)d_out;

    float* p = (float*)d_ws;
    float* gate_full = p; p += (size_t)Bv * NCv * CSv;
    float* bias_full = p; p += (size_t)Bv * NCv * CSv;
    float* s2   = p; p += (size_t)Bv * Nv * CSv;
    float* qc   = p; p += (size_t)Bv * Nv * HC;
    float* kc   = p; p += (size_t)Bv * Nv * HC;
    float* vc   = p; p += (size_t)Bv * Nv * HC;
    float* qpts = p; p += (size_t)Bv * Nv * QPD;
    float* kpts = p; p += (size_t)Bv * Nv * QPD;
    float* vpts = p; p += (size_t)Bv * Nv * (Hv * PVv * 3);
    float* qsq  = p; p += (size_t)Bv * Nv * Hv;
    float* ksq  = p; p += (size_t)Bv * Nv * Hv;
    float* bbias = p; p += (size_t)Bv * NBLKv * BQv * BKv * 12;
    float* pairz = p; p += (size_t)Bv * NBLKv * BQv * BKv * 32;
    float* feats = p; p += (size_t)Bv * Nv * FEAT;

    k_cond<<<Bv * NCv, 256, 0, stream>>>(cond, ln_cond_w, lin_cond_W, lin_cond_b,
                                         lin_cond_nb_W, gate_full, bias_full);
    k_s2<<<Bv * Nv, 128, 0, stream>>>(s, gate_full, bias_full, cidx, smask, s2);
    k_proj<<<Bv * Nv / 8, 256, 0, stream>>>(s2, Wq, Wk, Wv, Wqp, Wkvp, rots, trans,
                                            qc, kc, vc, qpts, kpts, vpts, qsq, ksq);
    k_zproj<<<Bv * NBLKv * BQv * BKv, 128, 0, stream>>>(z, ln_z_w, ln_z_b, Wb, Wdz,
                                                        bbias, pairz);
    k_attn<<<Bv * NBLKv * BQv, 128, 0, stream>>>(qc, kc, vc, qpts, kpts, vpts, qsq, ksq,
                                                 bbias, pairz, rots, trans, smask, head_w,
                                                 feats);
    k_out<<<dim3(64, 6), 256, 0, stream>>>(feats, Wout, out);
}

// Round 2
// 1166.155 us; speedup vs baseline: 2.1124x; 2.1124x over previous
//
#include <hip/hip_runtime.h>
#include <math.h>

// ---------------- constants ----------------
constexpr int Bv = 2, Nv = 2048, NCv = 256;
constexpr int CSv = 384, CCONDv = 256;
constexpr int CHv = 16, Hv = 12, PQKv = 4, PVv = 8;
constexpr int BQv = 32, BKv = 128, NBLKv = 64;
constexpr int HC = Hv * CHv;               // 192
constexpr int QPD = Hv * PQKv * 3;         // 144
constexpr int FEAT = 960;                  // H*CONCAT
constexpr float S1 = 0.14433756729740643f; // sqrt(1/48)
constexpr float S2 = 0.5773502691896258f;  // sqrt(1/3)
constexpr float HWS = 0.13608276348795434f;// sqrt(1/54)

typedef __attribute__((ext_vector_type(8))) short bf16x8;
typedef __attribute__((ext_vector_type(4))) float f32x4;

__device__ __forceinline__ short f2bf(float f) {
    unsigned u = __float_as_uint(f);
    u += 0x7FFF + ((u >> 16) & 1);
    return (short)(u >> 16);
}
__device__ __forceinline__ float bf2f(short s) {
    return __uint_as_float(((unsigned)(unsigned short)s) << 16);
}

// ---------------- helpers ----------------
__device__ __forceinline__ float blockReduceSum(float v, volatile float* red, int t, int nthr) {
    #pragma unroll
    for (int off = 32; off > 0; off >>= 1) v += __shfl_down(v, off, 64);
    int wid = t >> 6, lane = t & 63, nw = nthr >> 6;
    __syncthreads();
    if (lane == 0) red[wid] = v;
    __syncthreads();
    float r = 0.f;
    for (int w = 0; w < nw; ++w) r += red[w];
    return r;
}

// ---------------- K1: LN(cond) + gate/bias projections ----------------
__global__ __launch_bounds__(256) void k_cond(const float* __restrict__ cond,
                                              const float* __restrict__ lnw,
                                              const float* __restrict__ Wg,
                                              const float* __restrict__ bg,
                                              const float* __restrict__ Wnb,
                                              float* __restrict__ gate_full,
                                              float* __restrict__ bias_full) {
    __shared__ float cn[CCONDv];
    __shared__ float red[4];
    int row = blockIdx.x;          // b*NC + r
    int t = threadIdx.x;           // 256
    float c = cond[row * CCONDv + t];
    float mu = blockReduceSum(c, red, t, 256) * (1.f / CCONDv);
    float d = c - mu;
    float var = blockReduceSum(d * d, red, t, 256) * (1.f / CCONDv);
    cn[t] = d * rsqrtf(var + 1e-5f) * lnw[t];
    __syncthreads();
    for (int c0 = t; c0 < CSv; c0 += 256) {
        const float* w1 = Wg + (size_t)c0 * CCONDv;
        const float* w2 = Wnb + (size_t)c0 * CCONDv;
        float g = 0.f, bb = 0.f;
        for (int i = 0; i < CCONDv; ++i) { g += w1[i] * cn[i]; bb += w2[i] * cn[i]; }
        gate_full[row * CSv + c0] = g + bg[c0];
        bias_full[row * CSv + c0] = bb;
    }
}

// ---------------- K2: LN(s) + gather gate/bias -> s2 ----------------
__global__ __launch_bounds__(128) void k_s2(const float* __restrict__ s,
                                            const float* __restrict__ gate_full,
                                            const float* __restrict__ bias_full,
                                            const int* __restrict__ cidx,
                                            const float* __restrict__ smask,
                                            float* __restrict__ s2) {
    __shared__ float red[4];
    int row = blockIdx.x;          // b*N + n
    int t = threadIdx.x;           // 128
    const float* sr = s + (size_t)row * CSv;
    float x0 = sr[t], x1 = sr[t + 128], x2 = sr[t + 256];
    float mu = blockReduceSum(x0 + x1 + x2, red, t, 128) * (1.f / CSv);
    float d0 = x0 - mu, d1 = x1 - mu, d2 = x2 - mu;
    float var = blockReduceSum(d0 * d0 + d1 * d1 + d2 * d2, red, t, 128) * (1.f / CSv);
    float rs = rsqrtf(var + 1e-5f);
    int b = row / Nv;
    int ci = cidx[row];
    float m = smask[row];
    const float* gf = gate_full + (size_t)(b * NCv + ci) * CSv;
    const float* bf = bias_full + (size_t)(b * NCv + ci) * CSv;
    float dd[3] = {d0, d1, d2};
    #pragma unroll
    for (int j = 0; j < 3; ++j) {
        int cc = t + j * 128;
        float sn = dd[j] * rs;
        float g = gf[cc] * m, bi = bf[cc] * m;
        s2[(size_t)row * CSv + cc] = sn * (1.f / (1.f + expf(-g))) + bi;
    }
}

// ---------------- K3: per-row projections q/k/v/qpts/kpts/vpts/qsq/ksq ----------------
__global__ __launch_bounds__(256) void k_proj(const float* __restrict__ s2,
                                              const float* __restrict__ Wq,
                                              const float* __restrict__ Wk,
                                              const float* __restrict__ Wv,
                                              const float* __restrict__ Wqp,
                                              const float* __restrict__ Wkvp,
                                              const float* __restrict__ rots,
                                              const float* __restrict__ trans,
                                              float* __restrict__ qc, float* __restrict__ kc,
                                              float* __restrict__ vc,
                                              float* __restrict__ qpts, float* __restrict__ kpts,
                                              float* __restrict__ vpts,
                                              float* __restrict__ qsq, float* __restrict__ ksq) {
    __shared__ float s2t[8 * 385];
    __shared__ float outbuf[8 * 1156];
    __shared__ float Rl[8][9];
    __shared__ float trl[8][3];
    __shared__ float sqacc[8 * 24];
    int t = threadIdx.x;           // 256
    int n0 = blockIdx.x * 8;       // global row base (b*N+n)

    for (int idx = t; idx < 8 * CSv; idx += 256) {
        int r = idx / CSv, c = idx % CSv;
        s2t[r * 385 + c] = s2[(size_t)(n0 + r) * CSv + c];
    }
    for (int idx = t; idx < 72; idx += 256) Rl[idx / 9][idx % 9] = rots[(size_t)(n0 + idx / 9) * 9 + idx % 9];
    for (int idx = t; idx < 24; idx += 256) trl[idx / 3][idx % 3] = trans[(size_t)(n0 + idx / 3) * 3 + idx % 3];
    for (int idx = t; idx < 8 * 24; idx += 256) sqacc[idx] = 0.f;
    __syncthreads();

    // 1152 outputs per row
    for (int c = t; c < 1152; c += 256) {
        const float* w;
        if (c < 192) w = Wq + (size_t)c * CSv;
        else if (c < 384) w = Wk + (size_t)(c - 192) * CSv;
        else if (c < 576) w = Wv + (size_t)(c - 384) * CSv;
        else if (c < 720) w = Wqp + (size_t)(c - 576) * CSv;
        else w = Wkvp + (size_t)(c - 720) * CSv;
        float acc[8] = {0, 0, 0, 0, 0, 0, 0, 0};
        for (int i = 0; i < CSv; ++i) {
            float wv = w[i];
            #pragma unroll
            for (int r = 0; r < 8; ++r) acc[r] += wv * s2t[r * 385 + i];
        }
        #pragma unroll
        for (int r = 0; r < 8; ++r) outbuf[r * 1156 + c] = acc[r];
    }
    __syncthreads();

    // q/k/v copy out
    for (int idx = t; idx < 8 * 576; idx += 256) {
        int r = idx / 576, c = idx % 576;
        float val = outbuf[r * 1156 + c];
        size_t n = n0 + r;
        if (c < 192) qc[n * HC + c] = val;
        else if (c < 384) kc[n * HC + (c - 192)] = val;
        else vc[n * HC + (c - 384)] = val;
    }
    // q points: 48 per row
    for (int idx = t; idx < 8 * 48; idx += 256) {
        int r = idx / 48, p = idx % 48;
        float x = outbuf[r * 1156 + 576 + p * 3 + 0];
        float y = outbuf[r * 1156 + 576 + p * 3 + 1];
        float z = outbuf[r * 1156 + 576 + p * 3 + 2];
        const float* R = Rl[r];
        float ox = R[0] * x + R[1] * y + R[2] * z + trl[r][0];
        float oy = R[3] * x + R[4] * y + R[5] * z + trl[r][1];
        float oz = R[6] * x + R[7] * y + R[8] * z + trl[r][2];
        size_t n = n0 + r;
        qpts[n * QPD + p * 3 + 0] = ox;
        qpts[n * QPD + p * 3 + 1] = oy;
        qpts[n * QPD + p * 3 + 2] = oz;
        atomicAdd(&sqacc[r * 24 + p / PQKv], ox * ox + oy * oy + oz * oz);
    }
    // kv points: 144 per row
    for (int idx = t; idx < 8 * 144; idx += 256) {
        int r = idx / 144, p = idx % 144;
        float x = outbuf[r * 1156 + 720 + p * 3 + 0];
        float y = outbuf[r * 1156 + 720 + p * 3 + 1];
        float z = outbuf[r * 1156 + 720 + p * 3 + 2];
        const float* R = Rl[r];
        float ox = R[0] * x + R[1] * y + R[2] * z + trl[r][0];
        float oy = R[3] * x + R[4] * y + R[5] * z + trl[r][1];
        float oz = R[6] * x + R[7] * y + R[8] * z + trl[r][2];
        size_t n = n0 + r;
        int h = p / 12, pp = p % 12;
        if (pp < PQKv) {
            kpts[n * QPD + (h * PQKv + pp) * 3 + 0] = ox;
            kpts[n * QPD + (h * PQKv + pp) * 3 + 1] = oy;
            kpts[n * QPD + (h * PQKv + pp) * 3 + 2] = oz;
            atomicAdd(&sqacc[r * 24 + 12 + h], ox * ox + oy * oy + oz * oz);
        } else {
            vpts[n * (Hv * PVv * 3) + (h * PVv + pp - PQKv) * 3 + 0] = ox;
            vpts[n * (Hv * PVv * 3) + (h * PVv + pp - PQKv) * 3 + 1] = oy;
            vpts[n * (Hv * PVv * 3) + (h * PVv + pp - PQKv) * 3 + 2] = oz;
        }
    }
    __syncthreads();
    for (int idx = t; idx < 8 * 12; idx += 256) {
        int r = idx / 12, h = idx % 12;
        size_t n = n0 + r;
        qsq[n * Hv + h] = sqacc[r * 24 + h];
        ksq[n * Hv + h] = sqacc[r * 24 + 12 + h];
    }
}

// ---------------- K4a: precompute folded z-proj weights ----------------
// W'[c][i] = lnw[i]*w[c][i] (bf16), S[c]=sum_i W'[c][i], B[c]=dot(lnb, w[c])
// c in [0,44): 0..11 -> Wb rows, 12..43 -> Wdz rows. Cols 44..47 zero pad.
__global__ __launch_bounds__(256) void k_prep(const float* __restrict__ Wb,
                                              const float* __restrict__ Wdz,
                                              const float* __restrict__ lnw,
                                              const float* __restrict__ lnb,
                                              short* __restrict__ wp,
                                              float* __restrict__ SB) {
    int t = threadIdx.x;
    if (t < 176) {
        int c = t >> 2, q = t & 3;
        const float* wrow = (c < 12) ? (Wb + (size_t)c * 128) : (Wdz + (size_t)(c - 12) * 128);
        float sacc = 0.f, bacc = 0.f;
        for (int i = q * 32; i < q * 32 + 32; ++i) {
            float wf = wrow[i] * lnw[i];
            short bs = f2bf(wf);
            wp[c * 128 + i] = bs;
            sacc += bf2f(bs);
            bacc += lnb[i] * wrow[i];
        }
        sacc += __shfl_xor(sacc, 1, 64); sacc += __shfl_xor(sacc, 2, 64);
        bacc += __shfl_xor(bacc, 1, 64); bacc += __shfl_xor(bacc, 2, 64);
        if (q == 0) { SB[c] = sacc; SB[48 + c] = bacc; }
    }
    for (int i = t; i < 512; i += 256) wp[44 * 128 + i] = 0;
    if (t >= 176 && t < 180) { SB[t - 132] = 0.f; SB[48 + t - 132] = 0.f; }
}

// ---------------- K4b: fused LN(z)+proj via bf16 MFMA ----------------
// block = 128 z-rows (one (b,blk,q) slice), 256 threads = 4 waves.
// out[row][c] = rs_row*(dot_bf16(z_row, W'_c) - mu_row*S_c) + B_c
__global__ __launch_bounds__(256) void k_zproj2(const float* __restrict__ z,
                                                const short* __restrict__ wp,
                                                const float* __restrict__ SB,
                                                float* __restrict__ bbias,
                                                float* __restrict__ pairz) {
    __shared__ short zbuf[128 * 136];   // bf16, row stride 136 (272B, 2-way bank = free)
    __shared__ short wbuf[48 * 136];
    __shared__ float muL[128], rsL[128], SL[48], BL[48];
    int t = threadIdx.x;
    size_t row0 = (size_t)blockIdx.x * 128;

    // stage folded weights
    for (int idx = t; idx < 768; idx += 256) {
        int c = idx >> 4, k8 = idx & 15;
        uint4 v = *(const uint4*)(wp + c * 128 + k8 * 8);
        *(uint4*)&wbuf[c * 136 + k8 * 8] = v;
    }
    if (t < 96) {
        float v = SB[t];
        if (t < 48) SL[t] = v; else BL[t - 48] = v;
    }

    // stage z (coalesced float4), convert to bf16, per-row stats via shuffles
    const float4* zsrc = (const float4*)(z + row0 * 128);
    #pragma unroll
    for (int it = 0; it < 16; ++it) {
        int f = it * 256 + t;
        int r = f >> 5, c4 = f & 31;     // 32 float4 per row; 32 lanes cover a row
        float4 v = zsrc[f];
        short s0 = f2bf(v.x), s1 = f2bf(v.y), s2 = f2bf(v.z), s3 = f2bf(v.w);
        unsigned lo = ((unsigned)(unsigned short)s0) | (((unsigned)(unsigned short)s1) << 16);
        unsigned hi = ((unsigned)(unsigned short)s2) | (((unsigned)(unsigned short)s3) << 16);
        *(uint2*)&zbuf[r * 136 + c4 * 4] = make_uint2(lo, hi);
        float sm = v.x + v.y + v.z + v.w;
        float sq = v.x * v.x + v.y * v.y + v.z * v.z + v.w * v.w;
        #pragma unroll
        for (int off = 1; off <= 16; off <<= 1) {
            sm += __shfl_xor(sm, off, 64);
            sq += __shfl_xor(sq, off, 64);
        }
        if ((t & 31) == 0) {
            float mu = sm * (1.f / 128.f);
            float var = sq * (1.f / 128.f) - mu * mu;
            muL[r] = mu;
            rsL[r] = rsqrtf(var + 1e-5f);
        }
    }
    __syncthreads();

    // MFMA: wave w handles rows [w*32, w*32+32), all 48 cols. 2x3 tiles, K=128.
    int wv = t >> 6, lane = t & 63;
    int lr = lane & 15, quad = lane >> 4;
    int mb = wv * 32;
    f32x4 zero = 0;
    f32x4 acc[2][3];
    #pragma unroll
    for (int i = 0; i < 2; ++i)
        #pragma unroll
        for (int j = 0; j < 3; ++j) acc[i][j] = zero;
    #pragma unroll
    for (int kt = 0; kt < 4; ++kt) {
        int ko = kt * 32 + quad * 8;
        bf16x8 a0 = *(const bf16x8*)&zbuf[(mb + lr) * 136 + ko];
        bf16x8 a1 = *(const bf16x8*)&zbuf[(mb + 16 + lr) * 136 + ko];
        bf16x8 b0 = *(const bf16x8*)&wbuf[lr * 136 + ko];
        bf16x8 b1 = *(const bf16x8*)&wbuf[(16 + lr) * 136 + ko];
        bf16x8 b2 = *(const bf16x8*)&wbuf[(32 + lr) * 136 + ko];
        acc[0][0] = __builtin_amdgcn_mfma_f32_16x16x32_bf16(a0, b0, acc[0][0], 0, 0, 0);
        acc[0][1] = __builtin_amdgcn_mfma_f32_16x16x32_bf16(a0, b1, acc[0][1], 0, 0, 0);
        acc[0][2] = __builtin_amdgcn_mfma_f32_16x16x32_bf16(a0, b2, acc[0][2], 0, 0, 0);
        acc[1][0] = __builtin_amdgcn_mfma_f32_16x16x32_bf16(a1, b0, acc[1][0], 0, 0, 0);
        acc[1][1] = __builtin_amdgcn_mfma_f32_16x16x32_bf16(a1, b1, acc[1][1], 0, 0, 0);
        acc[1][2] = __builtin_amdgcn_mfma_f32_16x16x32_bf16(a1, b2, acc[1][2], 0, 0, 0);
    }

    // epilogue: D layout col=lane&15, row=quad*4+reg
    #pragma unroll
    for (int mt = 0; mt < 2; ++mt) {
        #pragma unroll
        for (int nt = 0; nt < 3; ++nt) {
            #pragma unroll
            for (int r4 = 0; r4 < 4; ++r4) {
                int rl = mb + mt * 16 + quad * 4 + r4;
                int col = nt * 16 + lr;
                float val = acc[mt][nt][r4];
                float outv = rsL[rl] * (val - muL[rl] * SL[col]) + BL[col];
                size_t grow = row0 + rl;
                if (col < 12) bbias[grow * 12 + col] = outv;
                else if (col < 44) pairz[grow * 32 + (col - 12)] = outv;
            }
        }
    }
}

// ---------------- K5: attention per (b, blk, q) ----------------
__global__ __launch_bounds__(128) void k_attn(const float* __restrict__ qc,
                                              const float* __restrict__ kc,
                                              const float* __restrict__ vc,
                                              const float* __restrict__ qpts,
                                              const float* __restrict__ kpts,
                                              const float* __restrict__ vpts,
                                              const float* __restrict__ qsq,
                                              const float* __restrict__ ksq,
                                              const float* __restrict__ bbias,
                                              const float* __restrict__ pairz,
                                              const float* __restrict__ rots,
                                              const float* __restrict__ trans,
                                              const float* __restrict__ smask,
                                              const float* __restrict__ head_w,
                                              float* __restrict__ feats) {
    __shared__ float qv[HC];
    __shared__ float qp_l[QPD];
    __shared__ float qsq_l[Hv];
    __shared__ float hwl[Hv];
    __shared__ float Rl[9];
    __shared__ float trl[3];
    __shared__ float Amat[Hv * BKv];
    __shared__ int nkg_l[BKv];
    __shared__ float featbuf[FEAT];
    __shared__ float optraw[Hv * PVv * 3];

    int t = threadIdx.x;           // 128
    int b = blockIdx.x / (NBLKv * BQv);
    int rem = blockIdx.x % (NBLKv * BQv);
    int blk = rem / BQv, qq = rem % BQv;
    int nq = blk * BQv + qq;
    int nqg = b * Nv + nq;
    int zbase = ((b * NBLKv + blk) * BQv + qq) * BKv;

    for (int i = t; i < HC; i += 128) qv[i] = qc[(size_t)nqg * HC + i];
    for (int i = t; i < QPD; i += 128) qp_l[i] = qpts[(size_t)nqg * QPD + i];
    if (t < Hv) {
        qsq_l[t] = qsq[(size_t)nqg * Hv + t];
        hwl[t] = log1pf(expf(head_w[t])) * HWS;
    }
    if (t < 9) Rl[t] = rots[(size_t)nqg * 9 + t];
    if (t < 3) trl[t] = trans[(size_t)nqg * 3 + t];
    float qm = smask[nqg];
    __syncthreads();

    // phase 1: logits
    {
        int kk = t;
        int nkrel = blk * BQv + kk - 48;
        bool valid = (nkrel >= 0) && (nkrel < Nv);
        int nkg = valid ? (b * Nv + nkrel) : -1;
        nkg_l[kk] = nkg;
        float km = valid ? smask[nkg] : 0.f;
        float Mterm = 1e5f * (qm * km - 1.f);
        for (int h = 0; h < Hv; ++h) {
            float dqk = 0.f, dpt = 0.f, ksqv = 0.f;
            if (valid) {
                const float* kr = kc + (size_t)nkg * HC + h * CHv;
                #pragma unroll
                for (int c = 0; c < CHv; ++c) dqk += qv[h * CHv + c] * kr[c];
                const float* kp = kpts + (size_t)nkg * QPD + h * 12;
                #pragma unroll
                for (int e = 0; e < 12; ++e) dpt += qp_l[h * 12 + e] * kp[e];
                ksqv = ksq[(size_t)nkg * Hv + h];
            }
            float hw = hwl[h];
            float logit = S1 * dqk + S2 * bbias[(size_t)(zbase + kk) * 12 + h]
                        + hw * dpt - 0.5f * hw * (qsq_l[h] + ksqv) + Mterm;
            Amat[h * BKv + kk] = logit;
        }
    }
    __syncthreads();

    // phase 2: softmax over k
    {
        int w = t >> 6, lane = t & 63;
        for (int h = w * 6; h < w * 6 + 6; ++h) {
            float v0 = Amat[h * BKv + lane], v1 = Amat[h * BKv + 64 + lane];
            float m = fmaxf(v0, v1);
            #pragma unroll
            for (int off = 32; off > 0; off >>= 1) m = fmaxf(m, __shfl_xor(m, off, 64));
            float e0 = expf(v0 - m), e1 = expf(v1 - m);
            float ssum = e0 + e1;
            #pragma unroll
            for (int off = 32; off > 0; off >>= 1) ssum += __shfl_xor(ssum, off, 64);
            float inv = 1.f / ssum;
            Amat[h * BKv + lane] = e0 * inv;
            Amat[h * BKv + 64 + lane] = e1 * inv;
        }
    }
    __syncthreads();

    // phase 3: weighted sums (864 outputs)
    for (int o = t; o < 864; o += 128) {
        float acc = 0.f;
        if (o < 192) {
            int h = o >> 4, c = o & 15;
            for (int k = 0; k < BKv; ++k) {
                int g = nkg_l[k];
                if (g >= 0) acc += Amat[h * BKv + k] * vc[(size_t)g * HC + h * CHv + c];
            }
            featbuf[o] = acc;
        } else if (o < 480) {
            int po = o - 192;
            int h = po / 24, r2 = po % 24;
            for (int k = 0; k < BKv; ++k) {
                int g = nkg_l[k];
                if (g >= 0) acc += Amat[h * BKv + k] * vpts[(size_t)g * (Hv * PVv * 3) + h * 24 + r2];
            }
            optraw[po] = acc;
        } else {
            int po = o - 480;
            int h = po >> 5, c = po & 31;
            for (int k = 0; k < BKv; ++k)
                acc += Amat[h * BKv + k] * pairz[(size_t)(zbase + k) * 32 + c];
            featbuf[576 + po] = acc;
        }
    }
    __syncthreads();

    // phase 4: rotate o_pt back to local frame + norms
    if (t < Hv * PVv) {
        float x = optraw[t * 3 + 0] - trl[0];
        float y = optraw[t * 3 + 1] - trl[1];
        float z = optraw[t * 3 + 2] - trl[2];
        float lx = Rl[0] * x + Rl[3] * y + Rl[6] * z;
        float ly = Rl[1] * x + Rl[4] * y + Rl[7] * z;
        float lz = Rl[2] * x + Rl[5] * y + Rl[8] * z;
        featbuf[192 + t * 3 + 0] = lx;
        featbuf[192 + t * 3 + 1] = ly;
        featbuf[192 + t * 3 + 2] = lz;
        featbuf[480 + t] = sqrtf(lx * lx + ly * ly + lz * lz + 1e-8f);
    }
    __syncthreads();
    for (int c = t; c < FEAT; c += 128) feats[(size_t)nqg * FEAT + c] = featbuf[c];
}

// ---------------- K6: out = feats @ Wout^T (4096x960x384) ----------------
__global__ __launch_bounds__(256) void k_out(const float* __restrict__ A,
                                             const float* __restrict__ Wo,
                                             float* __restrict__ C) {
    __shared__ float As[32][65];
    __shared__ float Bs[32][65];
    int t = threadIdx.x;
    int m0 = blockIdx.x * 64;
    int c0 = blockIdx.y * 64;
    int tx = t & 15, ty = t >> 4;
    int lr = t >> 2, lk = (t & 3) * 8;
    float acc[4][4] = {};
    for (int k0 = 0; k0 < FEAT; k0 += 32) {
        const float4* ap = (const float4*)(A + (size_t)(m0 + lr) * FEAT + k0 + lk);
        const float4* bp = (const float4*)(Wo + (size_t)(c0 + lr) * FEAT + k0 + lk);
        float4 a0 = ap[0], a1 = ap[1];
        float4 b0 = bp[0], b1 = bp[1];
        As[lk + 0][lr] = a0.x; As[lk + 1][lr] = a0.y; As[lk + 2][lr] = a0.z; As[lk + 3][lr] = a0.w;
        As[lk + 4][lr] = a1.x; As[lk + 5][lr] = a1.y; As[lk + 6][lr] = a1.z; As[lk + 7][lr] = a1.w;
        Bs[lk + 0][lr] = b0.x; Bs[lk + 1][lr] = b0.y; Bs[lk + 2][lr] = b0.z; Bs[lk + 3][lr] = b0.w;
        Bs[lk + 4][lr] = b1.x; Bs[lk + 5][lr] = b1.y; Bs[lk + 6][lr] = b1.z; Bs[lk + 7][lr] = b1.w;
        __syncthreads();
        #pragma unroll
        for (int kk = 0; kk < 32; ++kk) {
            float a4[4], b4[4];
            #pragma unroll
            for (int i = 0; i < 4; ++i) a4[i] = As[kk][ty * 4 + i];
            #pragma unroll
            for (int j = 0; j < 4; ++j) b4[j] = Bs[kk][tx * 4 + j];
            #pragma unroll
            for (int i = 0; i < 4; ++i)
                #pragma unroll
                for (int j = 0; j < 4; ++j) acc[i][j] += a4[i] * b4[j];
        }
        __syncthreads();
    }
    #pragma unroll
    for (int i = 0; i < 4; ++i)
        #pragma unroll
        for (int j = 0; j < 4; ++j)
            C[(size_t)(m0 + ty * 4 + i) * CSv + c0 + tx * 4 + j] = acc[i][j];
}

// ---------------- launch ----------------
extern "C" void kernel_launch(void* const* d_in, const int* in_sizes, int n_in,
                              void* d_out, int out_size, void* d_ws, size_t ws_size,
                              hipStream_t stream) {
    const float* s          = (const float*)d_in[0];
    const float* cond       = (const float*)d_in[1];
    const float* z          = (const float*)d_in[2];
    const float* trans      = (const float*)d_in[3];
    const float* rots       = (const float*)d_in[4];
    const float* smask      = (const float*)d_in[5];
    const int*   cidx       = (const int*)d_in[6];
    const float* ln_cond_w  = (const float*)d_in[7];
    const float* lin_cond_W = (const float*)d_in[8];
    const float* lin_cond_b = (const float*)d_in[9];
    const float* lin_cond_nb_W = (const float*)d_in[10];
    const float* ln_z_w     = (const float*)d_in[11];
    const float* ln_z_b     = (const float*)d_in[12];
    const float* Wq         = (const float*)d_in[13];
    const float* Wk         = (const float*)d_in[14];
    const float* Wv         = (const float*)d_in[15];
    const float* Wqp        = (const float*)d_in[16];
    const float* Wkvp       = (const float*)d_in[17];
    const float* Wb         = (const float*)d_in[18];
    const float* Wdz        = (const float*)d_in[19];
    const float* head_w     = (const float*)d_in[20];
    const float* Wout       = (const float*)d_in[21];
    float* out = (float*)d_out;

    float* p = (float*)d_ws;
    short* wp = (short*)p; p += 3072;        // 48*128 bf16 = 12288 B
    float* SBp = p; p += 96;                 // S[48] + B[48]
    float* gate_full = p; p += (size_t)Bv * NCv * CSv;
    float* bias_full = p; p += (size_t)Bv * NCv * CSv;
    float* s2   = p; p += (size_t)Bv * Nv * CSv;
    float* qc   = p; p += (size_t)Bv * Nv * HC;
    float* kc   = p; p += (size_t)Bv * Nv * HC;
    float* vc   = p; p += (size_t)Bv * Nv * HC;
    float* qpts = p; p += (size_t)Bv * Nv * QPD;
    float* kpts = p; p += (size_t)Bv * Nv * QPD;
    float* vpts = p; p += (size_t)Bv * Nv * (Hv * PVv * 3);
    float* qsq  = p; p += (size_t)Bv * Nv * Hv;
    float* ksq  = p; p += (size_t)Bv * Nv * Hv;
    float* bbias = p; p += (size_t)Bv * NBLKv * BQv * BKv * 12;
    float* pairz = p; p += (size_t)Bv * NBLKv * BQv * BKv * 32;
    float* feats = p; p += (size_t)Bv * Nv * FEAT;

    k_prep<<<1, 256, 0, stream>>>(Wb, Wdz, ln_z_w, ln_z_b, wp, SBp);
    k_cond<<<Bv * NCv, 256, 0, stream>>>(cond, ln_cond_w, lin_cond_W, lin_cond_b,
                                         lin_cond_nb_W, gate_full, bias_full);
    k_s2<<<Bv * Nv, 128, 0, stream>>>(s, gate_full, bias_full, cidx, smask, s2);
    k_proj<<<Bv * Nv / 8, 256, 0, stream>>>(s2, Wq, Wk, Wv, Wqp, Wkvp, rots, trans,
                                            qc, kc, vc, qpts, kpts, vpts, qsq, ksq);
    k_zproj2<<<Bv * NBLKv * BQv, 256, 0, stream>>>(z, wp, SBp, bbias, pairz);
    k_attn<<<Bv * NBLKv * BQv, 128, 0, stream>>>(qc, kc, vc, qpts, kpts, vpts, qsq, ksq,
                                                 bbias, pairz, rots, trans, smask, head_w,
                                                 feats);
    k_out<<<dim3(64, 6), 256, 0, stream>>>(feats, Wout, out);
}

// Round 3
// 839.633 us; speedup vs baseline: 2.9339x; 1.3889x over previous
//
#include <hip/hip_runtime.h>
#include <math.h>

// ---------------- constants ----------------
constexpr int Bv = 2, Nv = 2048, NCv = 256;
constexpr int CSv = 384, CCONDv = 256;
constexpr int CHv = 16, Hv = 12, PQKv = 4, PVv = 8;
constexpr int BQv = 32, BKv = 128, NBLKv = 64;
constexpr int HC = Hv * CHv;               // 192
constexpr int QPD = Hv * PQKv * 3;         // 144
constexpr int FEAT = 960;                  // H*CONCAT
constexpr float S1 = 0.14433756729740643f; // sqrt(1/48)
constexpr float S2 = 0.5773502691896258f;  // sqrt(1/3)
constexpr float HWS = 0.13608276348795434f;// sqrt(1/54)

typedef __attribute__((ext_vector_type(8))) short bf16x8;
typedef __attribute__((ext_vector_type(4))) float f32x4;

__device__ __forceinline__ short f2bf(float f) {
    unsigned u = __float_as_uint(f);
    u += 0x7FFF + ((u >> 16) & 1);
    return (short)(u >> 16);
}
__device__ __forceinline__ float bf2f(short s) {
    return __uint_as_float(((unsigned)(unsigned short)s) << 16);
}
__device__ __forceinline__ unsigned pk2(short lo, short hi) {
    return ((unsigned)(unsigned short)lo) | (((unsigned)(unsigned short)hi) << 16);
}

union BF8 { short s[8]; bf16x8 v; };

// ---------------- helpers ----------------
__device__ __forceinline__ float blockReduceSum(float v, volatile float* red, int t, int nthr) {
    #pragma unroll
    for (int off = 32; off > 0; off >>= 1) v += __shfl_down(v, off, 64);
    int wid = t >> 6, lane = t & 63, nw = nthr >> 6;
    __syncthreads();
    if (lane == 0) red[wid] = v;
    __syncthreads();
    float r = 0.f;
    for (int w = 0; w < nw; ++w) r += red[w];
    return r;
}

// ---------------- K1: LN(cond) + gate/bias projections ----------------
__global__ __launch_bounds__(256) void k_cond(const float* __restrict__ cond,
                                              const float* __restrict__ lnw,
                                              const float* __restrict__ Wg,
                                              const float* __restrict__ bg,
                                              const float* __restrict__ Wnb,
                                              float* __restrict__ gate_full,
                                              float* __restrict__ bias_full) {
    __shared__ float cn[CCONDv];
    __shared__ float red[4];
    int row = blockIdx.x;          // b*NC + r
    int t = threadIdx.x;           // 256
    float c = cond[row * CCONDv + t];
    float mu = blockReduceSum(c, red, t, 256) * (1.f / CCONDv);
    float d = c - mu;
    float var = blockReduceSum(d * d, red, t, 256) * (1.f / CCONDv);
    cn[t] = d * rsqrtf(var + 1e-5f) * lnw[t];
    __syncthreads();
    for (int c0 = t; c0 < CSv; c0 += 256) {
        const float* w1 = Wg + (size_t)c0 * CCONDv;
        const float* w2 = Wnb + (size_t)c0 * CCONDv;
        float g = 0.f, bb = 0.f;
        for (int i = 0; i < CCONDv; ++i) { g += w1[i] * cn[i]; bb += w2[i] * cn[i]; }
        gate_full[row * CSv + c0] = g + bg[c0];
        bias_full[row * CSv + c0] = bb;
    }
}

// ---------------- K2: LN(s) + gather gate/bias -> s2 ----------------
__global__ __launch_bounds__(128) void k_s2(const float* __restrict__ s,
                                            const float* __restrict__ gate_full,
                                            const float* __restrict__ bias_full,
                                            const int* __restrict__ cidx,
                                            const float* __restrict__ smask,
                                            float* __restrict__ s2) {
    __shared__ float red[4];
    int row = blockIdx.x;          // b*N + n
    int t = threadIdx.x;           // 128
    const float* sr = s + (size_t)row * CSv;
    float x0 = sr[t], x1 = sr[t + 128], x2 = sr[t + 256];
    float mu = blockReduceSum(x0 + x1 + x2, red, t, 128) * (1.f / CSv);
    float d0 = x0 - mu, d1 = x1 - mu, d2 = x2 - mu;
    float var = blockReduceSum(d0 * d0 + d1 * d1 + d2 * d2, red, t, 128) * (1.f / CSv);
    float rs = rsqrtf(var + 1e-5f);
    int b = row / Nv;
    int ci = cidx[row];
    float m = smask[row];
    const float* gf = gate_full + (size_t)(b * NCv + ci) * CSv;
    const float* bf = bias_full + (size_t)(b * NCv + ci) * CSv;
    float dd[3] = {d0, d1, d2};
    #pragma unroll
    for (int j = 0; j < 3; ++j) {
        int cc = t + j * 128;
        float sn = dd[j] * rs;
        float g = gf[cc] * m, bi = bf[cc] * m;
        s2[(size_t)row * CSv + cc] = sn * (1.f / (1.f + expf(-g))) + bi;
    }
}

// ---------------- K3: per-row projections q/k/v/qpts/kpts/vpts/qsq/ksq ----------------
__global__ __launch_bounds__(256) void k_proj(const float* __restrict__ s2,
                                              const float* __restrict__ Wq,
                                              const float* __restrict__ Wk,
                                              const float* __restrict__ Wv,
                                              const float* __restrict__ Wqp,
                                              const float* __restrict__ Wkvp,
                                              const float* __restrict__ rots,
                                              const float* __restrict__ trans,
                                              float* __restrict__ qc, float* __restrict__ kc,
                                              float* __restrict__ vc,
                                              float* __restrict__ qpts, float* __restrict__ kpts,
                                              float* __restrict__ vpts,
                                              float* __restrict__ qsq, float* __restrict__ ksq) {
    __shared__ float s2t[8 * 385];
    __shared__ float outbuf[8 * 1156];
    __shared__ float Rl[8][9];
    __shared__ float trl[8][3];
    __shared__ float sqacc[8 * 24];
    int t = threadIdx.x;           // 256
    int n0 = blockIdx.x * 8;       // global row base (b*N+n)

    for (int idx = t; idx < 8 * CSv; idx += 256) {
        int r = idx / CSv, c = idx % CSv;
        s2t[r * 385 + c] = s2[(size_t)(n0 + r) * CSv + c];
    }
    for (int idx = t; idx < 72; idx += 256) Rl[idx / 9][idx % 9] = rots[(size_t)(n0 + idx / 9) * 9 + idx % 9];
    for (int idx = t; idx < 24; idx += 256) trl[idx / 3][idx % 3] = trans[(size_t)(n0 + idx / 3) * 3 + idx % 3];
    for (int idx = t; idx < 8 * 24; idx += 256) sqacc[idx] = 0.f;
    __syncthreads();

    // 1152 outputs per row
    for (int c = t; c < 1152; c += 256) {
        const float* w;
        if (c < 192) w = Wq + (size_t)c * CSv;
        else if (c < 384) w = Wk + (size_t)(c - 192) * CSv;
        else if (c < 576) w = Wv + (size_t)(c - 384) * CSv;
        else if (c < 720) w = Wqp + (size_t)(c - 576) * CSv;
        else w = Wkvp + (size_t)(c - 720) * CSv;
        float acc[8] = {0, 0, 0, 0, 0, 0, 0, 0};
        for (int i = 0; i < CSv; ++i) {
            float wv = w[i];
            #pragma unroll
            for (int r = 0; r < 8; ++r) acc[r] += wv * s2t[r * 385 + i];
        }
        #pragma unroll
        for (int r = 0; r < 8; ++r) outbuf[r * 1156 + c] = acc[r];
    }
    __syncthreads();

    // q/k/v copy out
    for (int idx = t; idx < 8 * 576; idx += 256) {
        int r = idx / 576, c = idx % 576;
        float val = outbuf[r * 1156 + c];
        size_t n = n0 + r;
        if (c < 192) qc[n * HC + c] = val;
        else if (c < 384) kc[n * HC + (c - 192)] = val;
        else vc[n * HC + (c - 384)] = val;
    }
    // q points: 48 per row
    for (int idx = t; idx < 8 * 48; idx += 256) {
        int r = idx / 48, p = idx % 48;
        float x = outbuf[r * 1156 + 576 + p * 3 + 0];
        float y = outbuf[r * 1156 + 576 + p * 3 + 1];
        float z = outbuf[r * 1156 + 576 + p * 3 + 2];
        const float* R = Rl[r];
        float ox = R[0] * x + R[1] * y + R[2] * z + trl[r][0];
        float oy = R[3] * x + R[4] * y + R[5] * z + trl[r][1];
        float oz = R[6] * x + R[7] * y + R[8] * z + trl[r][2];
        size_t n = n0 + r;
        qpts[n * QPD + p * 3 + 0] = ox;
        qpts[n * QPD + p * 3 + 1] = oy;
        qpts[n * QPD + p * 3 + 2] = oz;
        atomicAdd(&sqacc[r * 24 + p / PQKv], ox * ox + oy * oy + oz * oz);
    }
    // kv points: 144 per row
    for (int idx = t; idx < 8 * 144; idx += 256) {
        int r = idx / 144, p = idx % 144;
        float x = outbuf[r * 1156 + 720 + p * 3 + 0];
        float y = outbuf[r * 1156 + 720 + p * 3 + 1];
        float z = outbuf[r * 1156 + 720 + p * 3 + 2];
        const float* R = Rl[r];
        float ox = R[0] * x + R[1] * y + R[2] * z + trl[r][0];
        float oy = R[3] * x + R[4] * y + R[5] * z + trl[r][1];
        float oz = R[6] * x + R[7] * y + R[8] * z + trl[r][2];
        size_t n = n0 + r;
        int h = p / 12, pp = p % 12;
        if (pp < PQKv) {
            kpts[n * QPD + (h * PQKv + pp) * 3 + 0] = ox;
            kpts[n * QPD + (h * PQKv + pp) * 3 + 1] = oy;
            kpts[n * QPD + (h * PQKv + pp) * 3 + 2] = oz;
            atomicAdd(&sqacc[r * 24 + 12 + h], ox * ox + oy * oy + oz * oz);
        } else {
            vpts[n * (Hv * PVv * 3) + (h * PVv + pp - PQKv) * 3 + 0] = ox;
            vpts[n * (Hv * PVv * 3) + (h * PVv + pp - PQKv) * 3 + 1] = oy;
            vpts[n * (Hv * PVv * 3) + (h * PVv + pp - PQKv) * 3 + 2] = oz;
        }
    }
    __syncthreads();
    for (int idx = t; idx < 8 * 12; idx += 256) {
        int r = idx / 12, h = idx % 12;
        size_t n = n0 + r;
        qsq[n * Hv + h] = sqacc[r * 24 + h];
        ksq[n * Hv + h] = sqacc[r * 24 + 12 + h];
    }
}

// ---------------- K4a: precompute folded z-proj weights ----------------
__global__ __launch_bounds__(256) void k_prep(const float* __restrict__ Wb,
                                              const float* __restrict__ Wdz,
                                              const float* __restrict__ lnw,
                                              const float* __restrict__ lnb,
                                              short* __restrict__ wp,
                                              float* __restrict__ SB) {
    int t = threadIdx.x;
    if (t < 176) {
        int c = t >> 2, q = t & 3;
        const float* wrow = (c < 12) ? (Wb + (size_t)c * 128) : (Wdz + (size_t)(c - 12) * 128);
        float sacc = 0.f, bacc = 0.f;
        for (int i = q * 32; i < q * 32 + 32; ++i) {
            float wf = wrow[i] * lnw[i];
            short bs = f2bf(wf);
            wp[c * 128 + i] = bs;
            sacc += bf2f(bs);
            bacc += lnb[i] * wrow[i];
        }
        sacc += __shfl_xor(sacc, 1, 64); sacc += __shfl_xor(sacc, 2, 64);
        bacc += __shfl_xor(bacc, 1, 64); bacc += __shfl_xor(bacc, 2, 64);
        if (q == 0) { SB[c] = sacc; SB[48 + c] = bacc; }
    }
    for (int i = t; i < 512; i += 256) wp[44 * 128 + i] = 0;
    if (t >= 176 && t < 180) { SB[t - 132] = 0.f; SB[48 + t - 132] = 0.f; }
}

// ---------------- K4b: fused LN(z)+proj via bf16 MFMA ----------------
// block = 128 z-rows (one (b,blk,q) slice), 256 threads = 4 waves.
// bbias2 layout: [bblk][h][q][k] fp32 ; pairzT layout: [bblk*32+q][c][k] bf16
__global__ __launch_bounds__(256) void k_zproj2(const float* __restrict__ z,
                                                const short* __restrict__ wp,
                                                const float* __restrict__ SB,
                                                float* __restrict__ bbias2,
                                                short* __restrict__ pairzT) {
    __shared__ short zbuf[128 * 136];
    __shared__ short wbuf[48 * 136];
    __shared__ float muL[128], rsL[128], SL[48], BL[48];
    int t = threadIdx.x;
    int bid = blockIdx.x;
    int bblk = bid >> 5, qq = bid & 31;
    size_t row0 = (size_t)bid * 128;

    for (int idx = t; idx < 768; idx += 256) {
        int c = idx >> 4, k8 = idx & 15;
        uint4 v = *(const uint4*)(wp + c * 128 + k8 * 8);
        *(uint4*)&wbuf[c * 136 + k8 * 8] = v;
    }
    if (t < 96) {
        float v = SB[t];
        if (t < 48) SL[t] = v; else BL[t - 48] = v;
    }

    const float4* zsrc = (const float4*)(z + row0 * 128);
    #pragma unroll
    for (int it = 0; it < 16; ++it) {
        int f = it * 256 + t;
        int r = f >> 5, c4 = f & 31;
        float4 v = zsrc[f];
        short s0 = f2bf(v.x), s1 = f2bf(v.y), s2v = f2bf(v.z), s3 = f2bf(v.w);
        *(uint2*)&zbuf[r * 136 + c4 * 4] = make_uint2(pk2(s0, s1), pk2(s2v, s3));
        float sm = v.x + v.y + v.z + v.w;
        float sq = v.x * v.x + v.y * v.y + v.z * v.z + v.w * v.w;
        #pragma unroll
        for (int off = 1; off <= 16; off <<= 1) {
            sm += __shfl_xor(sm, off, 64);
            sq += __shfl_xor(sq, off, 64);
        }
        if ((t & 31) == 0) {
            float mu = sm * (1.f / 128.f);
            float var = sq * (1.f / 128.f) - mu * mu;
            muL[r] = mu;
            rsL[r] = rsqrtf(var + 1e-5f);
        }
    }
    __syncthreads();

    int wv = t >> 6, lane = t & 63;
    int lr = lane & 15, quad = lane >> 4;
    int mb = wv * 32;
    f32x4 zero = 0;
    f32x4 acc[2][3];
    #pragma unroll
    for (int i = 0; i < 2; ++i)
        #pragma unroll
        for (int j = 0; j < 3; ++j) acc[i][j] = zero;
    #pragma unroll
    for (int kt = 0; kt < 4; ++kt) {
        int ko = kt * 32 + quad * 8;
        bf16x8 a0 = *(const bf16x8*)&zbuf[(mb + lr) * 136 + ko];
        bf16x8 a1 = *(const bf16x8*)&zbuf[(mb + 16 + lr) * 136 + ko];
        bf16x8 b0 = *(const bf16x8*)&wbuf[lr * 136 + ko];
        bf16x8 b1 = *(const bf16x8*)&wbuf[(16 + lr) * 136 + ko];
        bf16x8 b2 = *(const bf16x8*)&wbuf[(32 + lr) * 136 + ko];
        acc[0][0] = __builtin_amdgcn_mfma_f32_16x16x32_bf16(a0, b0, acc[0][0], 0, 0, 0);
        acc[0][1] = __builtin_amdgcn_mfma_f32_16x16x32_bf16(a0, b1, acc[0][1], 0, 0, 0);
        acc[0][2] = __builtin_amdgcn_mfma_f32_16x16x32_bf16(a0, b2, acc[0][2], 0, 0, 0);
        acc[1][0] = __builtin_amdgcn_mfma_f32_16x16x32_bf16(a1, b0, acc[1][0], 0, 0, 0);
        acc[1][1] = __builtin_amdgcn_mfma_f32_16x16x32_bf16(a1, b1, acc[1][1], 0, 0, 0);
        acc[1][2] = __builtin_amdgcn_mfma_f32_16x16x32_bf16(a1, b2, acc[1][2], 0, 0, 0);
    }

    float* bb_base = bbias2 + (size_t)(bblk * 12) * 4096 + qq * 128;
    short* pz_base = pairzT + (size_t)bid * 32 * 128;
    #pragma unroll
    for (int mt = 0; mt < 2; ++mt) {
        #pragma unroll
        for (int nt = 0; nt < 3; ++nt) {
            int col = nt * 16 + lr;
            int kbase = mb + mt * 16 + quad * 4;
            float ov[4];
            #pragma unroll
            for (int r4 = 0; r4 < 4; ++r4) {
                int rl = kbase + r4;
                ov[r4] = rsL[rl] * (acc[mt][nt][r4] - muL[rl] * SL[col]) + BL[col];
            }
            if (col < 12) {
                *(float4*)&bb_base[(size_t)col * 4096 + kbase] =
                    make_float4(ov[0], ov[1], ov[2], ov[3]);
            } else if (col < 44) {
                int c = col - 12;
                *(uint2*)&pz_base[c * 128 + kbase] =
                    make_uint2(pk2(f2bf(ov[0]), f2bf(ov[1])), pk2(f2bf(ov[2]), f2bf(ov[3])));
            }
        }
    }
}

// ---------------- K5a: attention logits+softmax+AV via MFMA ----------------
// grid = B*NBLK*2 (head-groups of 6); 512 threads = 8 waves.
__global__ __launch_bounds__(512) void k_attn_main(const float* __restrict__ qc,
                                                   const float* __restrict__ kc,
                                                   const float* __restrict__ vc,
                                                   const float* __restrict__ qpts,
                                                   const float* __restrict__ kpts,
                                                   const float* __restrict__ vpts,
                                                   const float* __restrict__ qsq,
                                                   const float* __restrict__ ksq,
                                                   const float* __restrict__ bbias2,
                                                   const float* __restrict__ smask,
                                                   const float* __restrict__ head_w,
                                                   short* __restrict__ Aws,
                                                   float* __restrict__ optraw,
                                                   float* __restrict__ feats) {
    __shared__ short kfrag[128 * 40];
    __shared__ short qfrag[32 * 40];
    __shared__ short vtile[128 * 48];
    __shared__ float sc[32 * 132];
    __shared__ short Abuf[32 * 136];
    __shared__ float rowb[32], qmL[32], colb[128], kmL[128];
    __shared__ int   nkgL[128];

    int t = threadIdx.x;
    int hg = blockIdx.x & 1;
    int bblk = blockIdx.x >> 1;
    int b = bblk >> 6, blk = bblk & 63;
    int wv = t >> 6, lane = t & 63;
    int lr = lane & 15, quad = lane >> 4;

    // window token indices (fixed for block)
    if (t < 128) {
        int nkrel = blk * BQv + t - 48;
        bool valid = (nkrel >= 0) && (nkrel < Nv);
        int nkg = valid ? (b * Nv + nkrel) : -1;
        nkgL[t] = nkg;
        kmL[t] = valid ? smask[nkg] : 0.f;
    }
    __syncthreads();

    for (int hh = 0; hh < 6; ++hh) {
        int h = hg * 6 + hh;
        float hw = log1pf(expf(head_w[h])) * HWS;

        // ---- stage K-frag, Q-frag, V-tile, biases ----
        {
            // kc -> kfrag[:, 0:16]
            int k = t >> 2, c4 = (t & 3) << 2;
            int g = nkgL[k];
            float4 v = (g >= 0) ? *(const float4*)&kc[(size_t)g * HC + h * 16 + c4]
                                : make_float4(0, 0, 0, 0);
            *(uint2*)&kfrag[k * 40 + c4] =
                make_uint2(pk2(f2bf(v.x), f2bf(v.y)), pk2(f2bf(v.z), f2bf(v.w)));
            // pad cols 28..31
            kfrag[k * 40 + 28 + (t & 3)] = 0;
        }
        if (t < 384) {
            // kpts -> kfrag[:, 16:28]
            int k = t / 3, c4 = (t % 3) * 4;
            int g = nkgL[k];
            float4 v = (g >= 0) ? *(const float4*)&kpts[(size_t)g * QPD + h * 12 + c4]
                                : make_float4(0, 0, 0, 0);
            *(uint2*)&kfrag[k * 40 + 16 + c4] =
                make_uint2(pk2(f2bf(v.x), f2bf(v.y)), pk2(f2bf(v.z), f2bf(v.w)));
        }
        if (t < 128) {
            int g = nkgL[t];
            colb[t] = (g >= 0) ? (-0.5f * hw * ksq[(size_t)g * Hv + h]) : 0.f;
            // qfrag: 32x16 q-channels (t<128 -> q=t>>2)
            int q = t >> 2, c4 = (t & 3) << 2;
            int nqg = b * Nv + blk * BQv + q;
            float4 v = *(const float4*)&qc[(size_t)nqg * HC + h * 16 + c4];
            *(uint2*)&qfrag[q * 40 + c4] =
                make_uint2(pk2(f2bf(S1 * v.x), f2bf(S1 * v.y)),
                           pk2(f2bf(S1 * v.z), f2bf(S1 * v.w)));
            qfrag[q * 40 + 28 + (t & 3)] = 0;
        }
        if (t < 96) {
            int q = t / 3, c4 = (t % 3) * 4;
            int nqg = b * Nv + blk * BQv + q;
            float4 v = *(const float4*)&qpts[(size_t)nqg * QPD + h * 12 + c4];
            *(uint2*)&qfrag[q * 40 + 16 + c4] =
                make_uint2(pk2(f2bf(hw * v.x), f2bf(hw * v.y)),
                           pk2(f2bf(hw * v.z), f2bf(hw * v.w)));
        }
        if (t < 32) {
            int nqg = b * Nv + blk * BQv + t;
            rowb[t] = -0.5f * hw * qsq[(size_t)nqg * Hv + t == t ? (size_t)nqg * Hv + h : 0];
            qmL[t] = smask[nqg];
        }
        // vtile: [k][48] (cols 0..15 vc, 16..39 vpts, 40..47 zero)
        for (int i = t; i < 128 * 48; i += 512) {
            int k = i / 48, c = i % 48;
            int g = nkgL[k];
            float v = 0.f;
            if (g >= 0) {
                if (c < 16) v = vc[(size_t)g * HC + h * 16 + c];
                else if (c < 40) v = vpts[(size_t)g * (Hv * PVv * 3) + h * 24 + (c - 16)];
            }
            vtile[k * 48 + c] = f2bf(v);
        }
        __syncthreads();

        // ---- logits MFMA: wave wv = n-tile (8), each does m-tiles 0,1 ----
        f32x4 d[2];
        d[0] = 0; d[1] = 0;
        {
            bf16x8 bfr = *(const bf16x8*)&kfrag[(wv * 16 + lr) * 40 + quad * 8];
            bf16x8 a0 = *(const bf16x8*)&qfrag[lr * 40 + quad * 8];
            bf16x8 a1 = *(const bf16x8*)&qfrag[(16 + lr) * 40 + quad * 8];
            d[0] = __builtin_amdgcn_mfma_f32_16x16x32_bf16(a0, bfr, d[0], 0, 0, 0);
            d[1] = __builtin_amdgcn_mfma_f32_16x16x32_bf16(a1, bfr, d[1], 0, 0, 0);
        }
        // epilogue -> sc
        {
            const float* bb = bbias2 + (size_t)(bblk * 12 + h) * 4096;
            #pragma unroll
            for (int mt = 0; mt < 2; ++mt) {
                #pragma unroll
                for (int r = 0; r < 4; ++r) {
                    int q = mt * 16 + quad * 4 + r;
                    int k = wv * 16 + lr;
                    float logit = d[mt][r] + rowb[q] + colb[k]
                                + 1e5f * (qmL[q] * kmL[k] - 1.f)
                                + S2 * bb[q * 128 + k];
                    sc[q * 132 + k] = logit;
                }
            }
        }
        __syncthreads();

        // ---- softmax: 16 threads per q-row, 8 k each ----
        {
            int q = t >> 4, i0 = (t & 15) * 8;
            float v[8];
            float m = -3.0e38f;
            #pragma unroll
            for (int j = 0; j < 8; ++j) { v[j] = sc[q * 132 + i0 + j]; m = fmaxf(m, v[j]); }
            #pragma unroll
            for (int off = 1; off <= 8; off <<= 1) m = fmaxf(m, __shfl_xor(m, off, 64));
            float ssum = 0.f;
            #pragma unroll
            for (int j = 0; j < 8; ++j) { v[j] = expf(v[j] - m); ssum += v[j]; }
            #pragma unroll
            for (int off = 1; off <= 8; off <<= 1) ssum += __shfl_xor(ssum, off, 64);
            float inv = 1.f / ssum;
            short a8[8];
            #pragma unroll
            for (int j = 0; j < 8; ++j) a8[j] = f2bf(v[j] * inv);
            uint4 packed = make_uint4(pk2(a8[0], a8[1]), pk2(a8[2], a8[3]),
                                      pk2(a8[4], a8[5]), pk2(a8[6], a8[7]));
            *(uint4*)&Abuf[q * 136 + i0] = packed;
            *(uint4*)&Aws[((size_t)(bblk * 32 + q) * 12 + h) * 128 + i0] = packed;
        }
        __syncthreads();

        // ---- AV MFMA: waves 0..5 -> (mt = wv&1, nt = wv>>1) ----
        if (wv < 6) {
            int mt = wv & 1, nt = wv >> 1;
            f32x4 acc = 0;
            #pragma unroll
            for (int kt = 0; kt < 4; ++kt) {
                bf16x8 a = *(const bf16x8*)&Abuf[(mt * 16 + lr) * 136 + quad * 8 + kt * 32];
                BF8 bb8;
                #pragma unroll
                for (int j = 0; j < 8; ++j)
                    bb8.s[j] = vtile[(kt * 32 + quad * 8 + j) * 48 + nt * 16 + lr];
                acc = __builtin_amdgcn_mfma_f32_16x16x32_bf16(a, bb8.v, acc, 0, 0, 0);
            }
            int c = nt * 16 + lr;
            #pragma unroll
            for (int r = 0; r < 4; ++r) {
                int q = mt * 16 + quad * 4 + r;
                size_t nqg = (size_t)b * Nv + blk * BQv + q;
                if (c < 16) feats[nqg * FEAT + h * 16 + c] = acc[r];
                else if (c < 40) optraw[nqg * 288 + h * 24 + (c - 16)] = acc[r];
            }
        }
        __syncthreads();
    }
}

// ---------------- K5b: o_pair (per q 12x128 @ 128x32) + rotation + feats ----------------
// grid = B*NBLK*BQ = 4096 blocks, 64 threads (1 wave).
__global__ __launch_bounds__(64) void k_pair(const short* __restrict__ Aws,
                                             const short* __restrict__ pairzT,
                                             const float* __restrict__ optraw,
                                             const float* __restrict__ rots,
                                             const float* __restrict__ trans,
                                             float* __restrict__ feats) {
    __shared__ unsigned apad_u[16 * 68];
    __shared__ unsigned ppad_u[32 * 68];
    __shared__ float Rt[12];
    int t = threadIdx.x;
    int bid = blockIdx.x;          // == nqg
    int lr = t & 15, quad = t >> 4;

    if (t < 9) Rt[t] = rots[(size_t)bid * 9 + t];
    if (t < 3) Rt[9 + t] = trans[(size_t)bid * 3 + t];

    const unsigned* Asrc = (const unsigned*)(Aws + (size_t)bid * 12 * 128);
    for (int i = t; i < 768; i += 64) {
        int h = i >> 6, w32 = i & 63;
        apad_u[h * 68 + w32] = Asrc[h * 64 + w32];
    }
    for (int i = t; i < 272; i += 64) apad_u[12 * 68 + i] = 0;
    const unsigned* Psrc = (const unsigned*)(pairzT + (size_t)bid * 32 * 128);
    for (int i = t; i < 2048; i += 64) {
        int c = i >> 6, w32 = i & 63;
        ppad_u[c * 68 + w32] = Psrc[c * 64 + w32];
    }
    __syncthreads();

    const short* apad = (const short*)apad_u;
    const short* ppad = (const short*)ppad_u;
    f32x4 acc0 = 0, acc1 = 0;
    #pragma unroll
    for (int kt = 0; kt < 4; ++kt) {
        int ko = quad * 8 + kt * 32;
        bf16x8 a = *(const bf16x8*)&apad[lr * 136 + ko];
        bf16x8 b0 = *(const bf16x8*)&ppad[lr * 136 + ko];
        bf16x8 b1 = *(const bf16x8*)&ppad[(16 + lr) * 136 + ko];
        acc0 = __builtin_amdgcn_mfma_f32_16x16x32_bf16(a, b0, acc0, 0, 0, 0);
        acc1 = __builtin_amdgcn_mfma_f32_16x16x32_bf16(a, b1, acc1, 0, 0, 0);
    }
    float* frow = feats + (size_t)bid * FEAT;
    #pragma unroll
    for (int r = 0; r < 4; ++r) {
        int hh = quad * 4 + r;
        if (hh < 12) {
            frow[576 + hh * 32 + lr] = acc0[r];
            frow[576 + hh * 32 + 16 + lr] = acc1[r];
        }
    }

    // rotate o_pt back to local frame + norms
    for (int p = t; p < 96; p += 64) {
        float x = optraw[(size_t)bid * 288 + p * 3 + 0] - Rt[9];
        float y = optraw[(size_t)bid * 288 + p * 3 + 1] - Rt[10];
        float z = optraw[(size_t)bid * 288 + p * 3 + 2] - Rt[11];
        float lx = Rt[0] * x + Rt[3] * y + Rt[6] * z;
        float ly = Rt[1] * x + Rt[4] * y + Rt[7] * z;
        float lz = Rt[2] * x + Rt[5] * y + Rt[8] * z;
        frow[192 + p * 3 + 0] = lx;
        frow[192 + p * 3 + 1] = ly;
        frow[192 + p * 3 + 2] = lz;
        frow[480 + p] = sqrtf(lx * lx + ly * ly + lz * lz + 1e-8f);
    }
}

// ---------------- K6: out = feats @ Wout^T (4096x960x384) ----------------
__global__ __launch_bounds__(256) void k_out(const float* __restrict__ A,
                                             const float* __restrict__ Wo,
                                             float* __restrict__ C) {
    __shared__ float As[32][65];
    __shared__ float Bs[32][65];
    int t = threadIdx.x;
    int m0 = blockIdx.x * 64;
    int c0 = blockIdx.y * 64;
    int tx = t & 15, ty = t >> 4;
    int lr = t >> 2, lk = (t & 3) * 8;
    float acc[4][4] = {};
    for (int k0 = 0; k0 < FEAT; k0 += 32) {
        const float4* ap = (const float4*)(A + (size_t)(m0 + lr) * FEAT + k0 + lk);
        const float4* bp = (const float4*)(Wo + (size_t)(c0 + lr) * FEAT + k0 + lk);
        float4 a0 = ap[0], a1 = ap[1];
        float4 b0 = bp[0], b1 = bp[1];
        As[lk + 0][lr] = a0.x; As[lk + 1][lr] = a0.y; As[lk + 2][lr] = a0.z; As[lk + 3][lr] = a0.w;
        As[lk + 4][lr] = a1.x; As[lk + 5][lr] = a1.y; As[lk + 6][lr] = a1.z; As[lk + 7][lr] = a1.w;
        Bs[lk + 0][lr] = b0.x; Bs[lk + 1][lr] = b0.y; Bs[lk + 2][lr] = b0.z; Bs[lk + 3][lr] = b0.w;
        Bs[lk + 4][lr] = b1.x; Bs[lk + 5][lr] = b1.y; Bs[lk + 6][lr] = b1.z; Bs[lk + 7][lr] = b1.w;
        __syncthreads();
        #pragma unroll
        for (int kk = 0; kk < 32; ++kk) {
            float a4[4], b4[4];
            #pragma unroll
            for (int i = 0; i < 4; ++i) a4[i] = As[kk][ty * 4 + i];
            #pragma unroll
            for (int j = 0; j < 4; ++j) b4[j] = Bs[kk][tx * 4 + j];
            #pragma unroll
            for (int i = 0; i < 4; ++i)
                #pragma unroll
                for (int j = 0; j < 4; ++j) acc[i][j] += a4[i] * b4[j];
        }
        __syncthreads();
    }
    #pragma unroll
    for (int i = 0; i < 4; ++i)
        #pragma unroll
        for (int j = 0; j < 4; ++j)
            C[(size_t)(m0 + ty * 4 + i) * CSv + c0 + tx * 4 + j] = acc[i][j];
}

// ---------------- launch ----------------
extern "C" void kernel_launch(void* const* d_in, const int* in_sizes, int n_in,
                              void* d_out, int out_size, void* d_ws, size_t ws_size,
                              hipStream_t stream) {
    const float* s          = (const float*)d_in[0];
    const float* cond       = (const float*)d_in[1];
    const float* z          = (const float*)d_in[2];
    const float* trans      = (const float*)d_in[3];
    const float* rots       = (const float*)d_in[4];
    const float* smask      = (const float*)d_in[5];
    const int*   cidx       = (const int*)d_in[6];
    const float* ln_cond_w  = (const float*)d_in[7];
    const float* lin_cond_W = (const float*)d_in[8];
    const float* lin_cond_b = (const float*)d_in[9];
    const float* lin_cond_nb_W = (const float*)d_in[10];
    const float* ln_z_w     = (const float*)d_in[11];
    const float* ln_z_b     = (const float*)d_in[12];
    const float* Wq         = (const float*)d_in[13];
    const float* Wk         = (const float*)d_in[14];
    const float* Wv         = (const float*)d_in[15];
    const float* Wqp        = (const float*)d_in[16];
    const float* Wkvp       = (const float*)d_in[17];
    const float* Wb         = (const float*)d_in[18];
    const float* Wdz        = (const float*)d_in[19];
    const float* head_w     = (const float*)d_in[20];
    const float* Wout       = (const float*)d_in[21];
    float* out = (float*)d_out;

    float* p = (float*)d_ws;
    short* wp = (short*)p; p += 3072;
    float* SBp = p; p += 96;
    float* gate_full = p; p += (size_t)Bv * NCv * CSv;
    float* bias_full = p; p += (size_t)Bv * NCv * CSv;
    float* s2   = p; p += (size_t)Bv * Nv * CSv;
    float* qc   = p; p += (size_t)Bv * Nv * HC;
    float* kc   = p; p += (size_t)Bv * Nv * HC;
    float* vc   = p; p += (size_t)Bv * Nv * HC;
    float* qpts = p; p += (size_t)Bv * Nv * QPD;
    float* kpts = p; p += (size_t)Bv * Nv * QPD;
    float* vpts = p; p += (size_t)Bv * Nv * (Hv * PVv * 3);
    float* qsq  = p; p += (size_t)Bv * Nv * Hv;
    float* ksq  = p; p += (size_t)Bv * Nv * Hv;
    float* bbias2 = p; p += (size_t)128 * 12 * 4096;            // 25.2 MB
    short* pairzT = (short*)p; p += (size_t)128 * 32 * 32 * 64; // 16.8M shorts
    short* Aws    = (short*)p; p += (size_t)4096 * 12 * 64;     // 6.3M shorts
    float* optraw = p; p += (size_t)4096 * 288;
    float* feats  = p; p += (size_t)Bv * Nv * FEAT;

    k_prep<<<1, 256, 0, stream>>>(Wb, Wdz, ln_z_w, ln_z_b, wp, SBp);
    k_cond<<<Bv * NCv, 256, 0, stream>>>(cond, ln_cond_w, lin_cond_W, lin_cond_b,
                                         lin_cond_nb_W, gate_full, bias_full);
    k_s2<<<Bv * Nv, 128, 0, stream>>>(s, gate_full, bias_full, cidx, smask, s2);
    k_proj<<<Bv * Nv / 8, 256, 0, stream>>>(s2, Wq, Wk, Wv, Wqp, Wkvp, rots, trans,
                                            qc, kc, vc, qpts, kpts, vpts, qsq, ksq);
    k_zproj2<<<Bv * NBLKv * BQv, 256, 0, stream>>>(z, wp, SBp, bbias2, pairzT);
    k_attn_main<<<Bv * NBLKv * 2, 512, 0, stream>>>(qc, kc, vc, qpts, kpts, vpts, qsq, ksq,
                                                    bbias2, smask, head_w, Aws, optraw, feats);
    k_pair<<<Bv * NBLKv * BQv, 64, 0, stream>>>(Aws, pairzT, optraw, rots, trans, feats);
    k_out<<<dim3(64, 6), 256, 0, stream>>>(feats, Wout, out);
}

// Round 4
// 649.400 us; speedup vs baseline: 3.7933x; 1.2929x over previous
//
#include <hip/hip_runtime.h>
#include <math.h>

// ---------------- constants ----------------
constexpr int Bv = 2, Nv = 2048, NCv = 256;
constexpr int CSv = 384, CCONDv = 256;
constexpr int CHv = 16, Hv = 12, PQKv = 4, PVv = 8;
constexpr int BQv = 32, BKv = 128, NBLKv = 64;
constexpr int HC = Hv * CHv;               // 192
constexpr int QPD = Hv * PQKv * 3;         // 144
constexpr int FEAT = 960;                  // H*CONCAT
constexpr int PROJW = 1152;                // q(192)+k(192)+v(192)+qp(144)+kvp(432)
constexpr float S1 = 0.14433756729740643f; // sqrt(1/48)
constexpr float S2 = 0.5773502691896258f;  // sqrt(1/3)
constexpr float HWS = 0.13608276348795434f;// sqrt(1/54)

typedef __attribute__((ext_vector_type(8))) short bf16x8;
typedef __attribute__((ext_vector_type(4))) float f32x4;

__device__ __forceinline__ short f2bf(float f) {
    unsigned u = __float_as_uint(f);
    u += 0x7FFF + ((u >> 16) & 1);
    return (short)(u >> 16);
}
__device__ __forceinline__ float bf2f(short s) {
    return __uint_as_float(((unsigned)(unsigned short)s) << 16);
}
__device__ __forceinline__ unsigned pk2(short lo, short hi) {
    return ((unsigned)(unsigned short)lo) | (((unsigned)(unsigned short)hi) << 16);
}

union BF8 { short s[8]; bf16x8 v; };

// ---------------- helpers ----------------
__device__ __forceinline__ float blockReduceSum(float v, volatile float* red, int t, int nthr) {
    #pragma unroll
    for (int off = 32; off > 0; off >>= 1) v += __shfl_down(v, off, 64);
    int wid = t >> 6, lane = t & 63, nw = nthr >> 6;
    __syncthreads();
    if (lane == 0) red[wid] = v;
    __syncthreads();
    float r = 0.f;
    for (int w = 0; w < nw; ++w) r += red[w];
    return r;
}

// ---------------- W0: convert weights to bf16 ----------------
// wsW  = [Wq;Wk;Wv;Wqp;Wkvp]  (1152 x 384)
// wsW2 = [Wg;Wnb]             (768 x 256)
__global__ __launch_bounds__(256) void k_wcvt(const float* __restrict__ Wq,
                                              const float* __restrict__ Wk,
                                              const float* __restrict__ Wv,
                                              const float* __restrict__ Wqp,
                                              const float* __restrict__ Wkvp,
                                              const float* __restrict__ Wg,
                                              const float* __restrict__ Wnb,
                                              short* __restrict__ wsW,
                                              short* __restrict__ wsW2) {
    int i4 = blockIdx.x * 256 + threadIdx.x;     // one float4 per thread
    int off = i4 * 4;
    const float* src;
    short* dst;
    int rel;
    if (off < 442368) {
        dst = wsW; rel = off;
        if (rel < 73728) src = Wq;
        else if (rel < 147456) { src = Wk; rel -= 73728; }
        else if (rel < 221184) { src = Wv; rel -= 147456; }
        else if (rel < 276480) { src = Wqp; rel -= 221184; }
        else { src = Wkvp; rel -= 276480; }
        float4 v = *(const float4*)(src + rel);
        *(uint2*)(dst + off) = make_uint2(pk2(f2bf(v.x), f2bf(v.y)), pk2(f2bf(v.z), f2bf(v.w)));
    } else if (off < 442368 + 196608) {
        int o2 = off - 442368;
        rel = o2;
        if (rel < 98304) src = Wg; else { src = Wnb; rel -= 98304; }
        float4 v = *(const float4*)(src + rel);
        *(uint2*)(wsW2 + o2) = make_uint2(pk2(f2bf(v.x), f2bf(v.y)), pk2(f2bf(v.z), f2bf(v.w)));
    }
}

// ---------------- generic bf16 GEMM: C[m][n] = sum_k A[m][k]*B[n][k] ----------------
// 128x128 tile, BK=32, 256 threads (4 waves, 64x64 quadrant each). M,N %128==0, K%32==0.
__global__ __launch_bounds__(256) void k_gemm_bt(const short* __restrict__ A,
                                                 const short* __restrict__ B,
                                                 float* __restrict__ C,
                                                 int K, int ldc) {
    __shared__ short As[128 * 40];
    __shared__ short Bs[128 * 40];
    int t = threadIdx.x;
    int m0 = blockIdx.x * 128, n0 = blockIdx.y * 128;
    int wv = t >> 6, lane = t & 63, lr = lane & 15, quad = lane >> 4;
    int mq = (wv & 1) * 64, nq = (wv >> 1) * 64;
    f32x4 acc[4][4];
    #pragma unroll
    for (int i = 0; i < 4; ++i)
        #pragma unroll
        for (int j = 0; j < 4; ++j) acc[i][j] = 0;

    int r0 = t >> 2, c8 = (t & 3) * 8;          // staging: idx t and t+256
    int r1 = (t + 256) >> 2, c81 = ((t + 256) & 3) * 8;

    for (int k0 = 0; k0 < K; k0 += 32) {
        uint4 a0 = *(const uint4*)(A + (size_t)(m0 + r0) * K + k0 + c8);
        uint4 a1 = *(const uint4*)(A + (size_t)(m0 + r1) * K + k0 + c81);
        uint4 b0 = *(const uint4*)(B + (size_t)(n0 + r0) * K + k0 + c8);
        uint4 b1 = *(const uint4*)(B + (size_t)(n0 + r1) * K + k0 + c81);
        *(uint4*)&As[r0 * 40 + c8] = a0;
        *(uint4*)&As[r1 * 40 + c81] = a1;
        *(uint4*)&Bs[r0 * 40 + c8] = b0;
        *(uint4*)&Bs[r1 * 40 + c81] = b1;
        __syncthreads();
        bf16x8 af[4], bf[4];
        #pragma unroll
        for (int i = 0; i < 4; ++i) {
            af[i] = *(const bf16x8*)&As[(mq + i * 16 + lr) * 40 + quad * 8];
            bf[i] = *(const bf16x8*)&Bs[(nq + i * 16 + lr) * 40 + quad * 8];
        }
        #pragma unroll
        for (int i = 0; i < 4; ++i)
            #pragma unroll
            for (int j = 0; j < 4; ++j)
                acc[i][j] = __builtin_amdgcn_mfma_f32_16x16x32_bf16(af[i], bf[j], acc[i][j], 0, 0, 0);
        __syncthreads();
    }
    #pragma unroll
    for (int i = 0; i < 4; ++i) {
        #pragma unroll
        for (int j = 0; j < 4; ++j) {
            int col = n0 + nq + j * 16 + lr;
            #pragma unroll
            for (int r = 0; r < 4; ++r) {
                int row = m0 + mq + i * 16 + quad * 4 + r;
                C[(size_t)row * ldc + col] = acc[i][j][r];
            }
        }
    }
}

// ---------------- K1: LN(cond) -> bf16 ----------------
__global__ __launch_bounds__(256) void k_condln(const float* __restrict__ cond,
                                                const float* __restrict__ lnw,
                                                short* __restrict__ cnbf) {
    __shared__ float red[4];
    int row = blockIdx.x;
    int t = threadIdx.x;
    float c = cond[row * CCONDv + t];
    float mu = blockReduceSum(c, red, t, 256) * (1.f / CCONDv);
    float d = c - mu;
    float var = blockReduceSum(d * d, red, t, 256) * (1.f / CCONDv);
    cnbf[row * CCONDv + t] = f2bf(d * rsqrtf(var + 1e-5f) * lnw[t]);
}

// ---------------- K2: LN(s) + gather gate/bias -> s2 (bf16) ----------------
__global__ __launch_bounds__(128) void k_s2(const float* __restrict__ s,
                                            const float* __restrict__ gb,
                                            const float* __restrict__ bg,
                                            const int* __restrict__ cidx,
                                            const float* __restrict__ smask,
                                            short* __restrict__ s2bf) {
    __shared__ float red[4];
    int row = blockIdx.x;          // b*N + n
    int t = threadIdx.x;           // 128
    const float* sr = s + (size_t)row * CSv;
    float x0 = sr[t], x1 = sr[t + 128], x2 = sr[t + 256];
    float mu = blockReduceSum(x0 + x1 + x2, red, t, 128) * (1.f / CSv);
    float d0 = x0 - mu, d1 = x1 - mu, d2 = x2 - mu;
    float var = blockReduceSum(d0 * d0 + d1 * d1 + d2 * d2, red, t, 128) * (1.f / CSv);
    float rs = rsqrtf(var + 1e-5f);
    int b = row / Nv;
    int ci = cidx[row];
    float m = smask[row];
    const float* gbr = gb + (size_t)(b * NCv + ci) * 768;
    float dd[3] = {d0, d1, d2};
    #pragma unroll
    for (int j = 0; j < 3; ++j) {
        int cc = t + j * 128;
        float sn = dd[j] * rs;
        float g = (gbr[cc] + bg[cc]) * m, bi = gbr[384 + cc] * m;
        s2bf[(size_t)row * CSv + cc] = f2bf(sn * (1.f / (1.f + expf(-g))) + bi);
    }
}

// ---------------- K3b: point rotation + qsq/ksq from proj ----------------
// grid = 4096 blocks x 192 threads (one point per thread)
__global__ __launch_bounds__(192) void k_post(const float* __restrict__ proj,
                                              const float* __restrict__ rots,
                                              const float* __restrict__ trans,
                                              float* __restrict__ qpts,
                                              float* __restrict__ kpts,
                                              float* __restrict__ vpts,
                                              float* __restrict__ qsq,
                                              float* __restrict__ ksq) {
    __shared__ float R[9], tr[3];
    int row = blockIdx.x;
    int t = threadIdx.x;
    if (t < 9) R[t] = rots[(size_t)row * 9 + t];
    if (t < 3) tr[t] = trans[(size_t)row * 3 + t];
    __syncthreads();
    const float* pr = proj + (size_t)row * PROJW + 576;
    float x = pr[t * 3 + 0], y = pr[t * 3 + 1], z = pr[t * 3 + 2];
    float ox = R[0] * x + R[1] * y + R[2] * z + tr[0];
    float oy = R[3] * x + R[4] * y + R[5] * z + tr[1];
    float oz = R[6] * x + R[7] * y + R[8] * z + tr[2];
    float sq = ox * ox + oy * oy + oz * oz;
    if (t < 48) {
        qpts[(size_t)row * QPD + t * 3 + 0] = ox;
        qpts[(size_t)row * QPD + t * 3 + 1] = oy;
        qpts[(size_t)row * QPD + t * 3 + 2] = oz;
        float s4 = sq + __shfl_xor(sq, 1, 64);
        s4 += __shfl_xor(s4, 2, 64);
        if ((t & 3) == 0) qsq[(size_t)row * Hv + (t >> 2)] = s4;
    } else {
        int p = t - 48;
        int h = p / 12, pp = p % 12;
        if (pp < PQKv) {
            kpts[(size_t)row * QPD + (h * PQKv + pp) * 3 + 0] = ox;
            kpts[(size_t)row * QPD + (h * PQKv + pp) * 3 + 1] = oy;
            kpts[(size_t)row * QPD + (h * PQKv + pp) * 3 + 2] = oz;
            float s4 = sq + __shfl_xor(sq, 1, 64);
            s4 += __shfl_xor(s4, 2, 64);
            if (pp == 0) ksq[(size_t)row * Hv + h] = s4;
        } else {
            int vi = h * PVv + pp - PQKv;
            vpts[(size_t)row * (Hv * PVv * 3) + vi * 3 + 0] = ox;
            vpts[(size_t)row * (Hv * PVv * 3) + vi * 3 + 1] = oy;
            vpts[(size_t)row * (Hv * PVv * 3) + vi * 3 + 2] = oz;
        }
    }
}

// ---------------- K4a: precompute folded z-proj weights ----------------
__global__ __launch_bounds__(256) void k_prep(const float* __restrict__ Wb,
                                              const float* __restrict__ Wdz,
                                              const float* __restrict__ lnw,
                                              const float* __restrict__ lnb,
                                              short* __restrict__ wp,
                                              float* __restrict__ SB) {
    int t = threadIdx.x;
    if (t < 176) {
        int c = t >> 2, q = t & 3;
        const float* wrow = (c < 12) ? (Wb + (size_t)c * 128) : (Wdz + (size_t)(c - 12) * 128);
        float sacc = 0.f, bacc = 0.f;
        for (int i = q * 32; i < q * 32 + 32; ++i) {
            float wf = wrow[i] * lnw[i];
            short bs = f2bf(wf);
            wp[c * 128 + i] = bs;
            sacc += bf2f(bs);
            bacc += lnb[i] * wrow[i];
        }
        sacc += __shfl_xor(sacc, 1, 64); sacc += __shfl_xor(sacc, 2, 64);
        bacc += __shfl_xor(bacc, 1, 64); bacc += __shfl_xor(bacc, 2, 64);
        if (q == 0) { SB[c] = sacc; SB[48 + c] = bacc; }
    }
    for (int i = t; i < 512; i += 256) wp[44 * 128 + i] = 0;
    if (t >= 176 && t < 180) { SB[t - 132] = 0.f; SB[48 + t - 132] = 0.f; }
}

// ---------------- K4b: fused LN(z)+proj via bf16 MFMA ----------------
__global__ __launch_bounds__(256) void k_zproj2(const float* __restrict__ z,
                                                const short* __restrict__ wp,
                                                const float* __restrict__ SB,
                                                float* __restrict__ bbias2,
                                                short* __restrict__ pairzT) {
    __shared__ short zbuf[128 * 136];
    __shared__ short wbuf[48 * 136];
    __shared__ float muL[128], rsL[128], SL[48], BL[48];
    int t = threadIdx.x;
    int bid = blockIdx.x;
    int bblk = bid >> 5, qq = bid & 31;
    size_t row0 = (size_t)bid * 128;

    for (int idx = t; idx < 768; idx += 256) {
        int c = idx >> 4, k8 = idx & 15;
        uint4 v = *(const uint4*)(wp + c * 128 + k8 * 8);
        *(uint4*)&wbuf[c * 136 + k8 * 8] = v;
    }
    if (t < 96) {
        float v = SB[t];
        if (t < 48) SL[t] = v; else BL[t - 48] = v;
    }

    const float4* zsrc = (const float4*)(z + row0 * 128);
    #pragma unroll
    for (int it = 0; it < 16; ++it) {
        int f = it * 256 + t;
        int r = f >> 5, c4 = f & 31;
        float4 v = zsrc[f];
        short s0 = f2bf(v.x), s1 = f2bf(v.y), s2v = f2bf(v.z), s3 = f2bf(v.w);
        *(uint2*)&zbuf[r * 136 + c4 * 4] = make_uint2(pk2(s0, s1), pk2(s2v, s3));
        float sm = v.x + v.y + v.z + v.w;
        float sq = v.x * v.x + v.y * v.y + v.z * v.z + v.w * v.w;
        #pragma unroll
        for (int off = 1; off <= 16; off <<= 1) {
            sm += __shfl_xor(sm, off, 64);
            sq += __shfl_xor(sq, off, 64);
        }
        if ((t & 31) == 0) {
            float mu = sm * (1.f / 128.f);
            float var = sq * (1.f / 128.f) - mu * mu;
            muL[r] = mu;
            rsL[r] = rsqrtf(var + 1e-5f);
        }
    }
    __syncthreads();

    int wv = t >> 6, lane = t & 63;
    int lr = lane & 15, quad = lane >> 4;
    int mb = wv * 32;
    f32x4 acc[2][3];
    #pragma unroll
    for (int i = 0; i < 2; ++i)
        #pragma unroll
        for (int j = 0; j < 3; ++j) acc[i][j] = 0;
    #pragma unroll
    for (int kt = 0; kt < 4; ++kt) {
        int ko = kt * 32 + quad * 8;
        bf16x8 a0 = *(const bf16x8*)&zbuf[(mb + lr) * 136 + ko];
        bf16x8 a1 = *(const bf16x8*)&zbuf[(mb + 16 + lr) * 136 + ko];
        bf16x8 b0 = *(const bf16x8*)&wbuf[lr * 136 + ko];
        bf16x8 b1 = *(const bf16x8*)&wbuf[(16 + lr) * 136 + ko];
        bf16x8 b2 = *(const bf16x8*)&wbuf[(32 + lr) * 136 + ko];
        acc[0][0] = __builtin_amdgcn_mfma_f32_16x16x32_bf16(a0, b0, acc[0][0], 0, 0, 0);
        acc[0][1] = __builtin_amdgcn_mfma_f32_16x16x32_bf16(a0, b1, acc[0][1], 0, 0, 0);
        acc[0][2] = __builtin_amdgcn_mfma_f32_16x16x32_bf16(a0, b2, acc[0][2], 0, 0, 0);
        acc[1][0] = __builtin_amdgcn_mfma_f32_16x16x32_bf16(a1, b0, acc[1][0], 0, 0, 0);
        acc[1][1] = __builtin_amdgcn_mfma_f32_16x16x32_bf16(a1, b1, acc[1][1], 0, 0, 0);
        acc[1][2] = __builtin_amdgcn_mfma_f32_16x16x32_bf16(a1, b2, acc[1][2], 0, 0, 0);
    }

    float* bb_base = bbias2 + (size_t)(bblk * 12) * 4096 + qq * 128;
    short* pz_base = pairzT + (size_t)bid * 32 * 128;
    #pragma unroll
    for (int mt = 0; mt < 2; ++mt) {
        #pragma unroll
        for (int nt = 0; nt < 3; ++nt) {
            int col = nt * 16 + lr;
            int kbase = mb + mt * 16 + quad * 4;
            float ov[4];
            #pragma unroll
            for (int r4 = 0; r4 < 4; ++r4) {
                int rl = kbase + r4;
                ov[r4] = rsL[rl] * (acc[mt][nt][r4] - muL[rl] * SL[col]) + BL[col];
            }
            if (col < 12) {
                *(float4*)&bb_base[(size_t)col * 4096 + kbase] =
                    make_float4(ov[0], ov[1], ov[2], ov[3]);
            } else if (col < 44) {
                int c = col - 12;
                *(uint2*)&pz_base[c * 128 + kbase] =
                    make_uint2(pk2(f2bf(ov[0]), f2bf(ov[1])), pk2(f2bf(ov[2]), f2bf(ov[3])));
            }
        }
    }
}

// ---------------- K5a: attention logits+softmax+AV via MFMA ----------------
// grid = B*NBLK*2 (head-groups of 6); 512 threads = 8 waves.
__global__ __launch_bounds__(512) void k_attn_main(const float* __restrict__ proj,
                                                   const float* __restrict__ qpts,
                                                   const float* __restrict__ kpts,
                                                   const float* __restrict__ vpts,
                                                   const float* __restrict__ qsq,
                                                   const float* __restrict__ ksq,
                                                   const float* __restrict__ bbias2,
                                                   const float* __restrict__ smask,
                                                   const float* __restrict__ head_w,
                                                   short* __restrict__ Aws,
                                                   float* __restrict__ optraw,
                                                   float* __restrict__ feats) {
    __shared__ short kfrag[128 * 40];
    __shared__ short qfrag[32 * 40];
    __shared__ short vtile[128 * 48];
    __shared__ float sc[32 * 132];
    __shared__ short Abuf[32 * 136];
    __shared__ float rowb[32], qmL[32], colb[128], kmL[128];
    __shared__ int   nkgL[128];

    int t = threadIdx.x;
    int hg = blockIdx.x & 1;
    int bblk = blockIdx.x >> 1;
    int b = bblk >> 6, blk = bblk & 63;
    int wv = t >> 6, lane = t & 63;
    int lr = lane & 15, quad = lane >> 4;

    if (t < 128) {
        int nkrel = blk * BQv + t - 48;
        bool valid = (nkrel >= 0) && (nkrel < Nv);
        int nkg = valid ? (b * Nv + nkrel) : -1;
        nkgL[t] = nkg;
        kmL[t] = valid ? smask[nkg] : 0.f;
    }
    __syncthreads();

    for (int hh = 0; hh < 6; ++hh) {
        int h = hg * 6 + hh;
        float hw = log1pf(expf(head_w[h])) * HWS;

        // ---- stage K-frag, Q-frag, V-tile, biases ----
        {
            int k = t >> 2, c4 = (t & 3) << 2;
            int g = nkgL[k];
            float4 v = (g >= 0) ? *(const float4*)&proj[(size_t)g * PROJW + 192 + h * 16 + c4]
                                : make_float4(0, 0, 0, 0);
            *(uint2*)&kfrag[k * 40 + c4] =
                make_uint2(pk2(f2bf(v.x), f2bf(v.y)), pk2(f2bf(v.z), f2bf(v.w)));
            kfrag[k * 40 + 28 + (t & 3)] = 0;
        }
        if (t < 384) {
            int k = t / 3, c4 = (t % 3) * 4;
            int g = nkgL[k];
            float4 v = (g >= 0) ? *(const float4*)&kpts[(size_t)g * QPD + h * 12 + c4]
                                : make_float4(0, 0, 0, 0);
            *(uint2*)&kfrag[k * 40 + 16 + c4] =
                make_uint2(pk2(f2bf(v.x), f2bf(v.y)), pk2(f2bf(v.z), f2bf(v.w)));
        }
        if (t < 128) {
            int g = nkgL[t];
            colb[t] = (g >= 0) ? (-0.5f * hw * ksq[(size_t)g * Hv + h]) : 0.f;
            int q = t >> 2, c4 = (t & 3) << 2;
            int nqg = b * Nv + blk * BQv + q;
            float4 v = *(const float4*)&proj[(size_t)nqg * PROJW + h * 16 + c4];
            *(uint2*)&qfrag[q * 40 + c4] =
                make_uint2(pk2(f2bf(S1 * v.x), f2bf(S1 * v.y)),
                           pk2(f2bf(S1 * v.z), f2bf(S1 * v.w)));
            qfrag[q * 40 + 28 + (t & 3)] = 0;
        }
        if (t < 96) {
            int q = t / 3, c4 = (t % 3) * 4;
            int nqg = b * Nv + blk * BQv + q;
            float4 v = *(const float4*)&qpts[(size_t)nqg * QPD + h * 12 + c4];
            *(uint2*)&qfrag[q * 40 + 16 + c4] =
                make_uint2(pk2(f2bf(hw * v.x), f2bf(hw * v.y)),
                           pk2(f2bf(hw * v.z), f2bf(hw * v.w)));
        }
        if (t < 32) {
            int nqg = b * Nv + blk * BQv + t;
            rowb[t] = -0.5f * hw * qsq[(size_t)nqg * Hv + h];
            qmL[t] = smask[nqg];
        }
        for (int i = t; i < 128 * 48; i += 512) {
            int k = i / 48, c = i % 48;
            int g = nkgL[k];
            float v = 0.f;
            if (g >= 0) {
                if (c < 16) v = proj[(size_t)g * PROJW + 384 + h * 16 + c];
                else if (c < 40) v = vpts[(size_t)g * (Hv * PVv * 3) + h * 24 + (c - 16)];
            }
            vtile[k * 48 + c] = f2bf(v);
        }
        __syncthreads();

        // ---- logits MFMA ----
        f32x4 d[2];
        d[0] = 0; d[1] = 0;
        {
            bf16x8 bfr = *(const bf16x8*)&kfrag[(wv * 16 + lr) * 40 + quad * 8];
            bf16x8 a0 = *(const bf16x8*)&qfrag[lr * 40 + quad * 8];
            bf16x8 a1 = *(const bf16x8*)&qfrag[(16 + lr) * 40 + quad * 8];
            d[0] = __builtin_amdgcn_mfma_f32_16x16x32_bf16(a0, bfr, d[0], 0, 0, 0);
            d[1] = __builtin_amdgcn_mfma_f32_16x16x32_bf16(a1, bfr, d[1], 0, 0, 0);
        }
        {
            const float* bb = bbias2 + (size_t)(bblk * 12 + h) * 4096;
            #pragma unroll
            for (int mt = 0; mt < 2; ++mt) {
                #pragma unroll
                for (int r = 0; r < 4; ++r) {
                    int q = mt * 16 + quad * 4 + r;
                    int k = wv * 16 + lr;
                    float logit = d[mt][r] + rowb[q] + colb[k]
                                + 1e5f * (qmL[q] * kmL[k] - 1.f)
                                + S2 * bb[q * 128 + k];
                    sc[q * 132 + k] = logit;
                }
            }
        }
        __syncthreads();

        // ---- softmax ----
        {
            int q = t >> 4, i0 = (t & 15) * 8;
            float v[8];
            float m = -3.0e38f;
            #pragma unroll
            for (int j = 0; j < 8; ++j) { v[j] = sc[q * 132 + i0 + j]; m = fmaxf(m, v[j]); }
            #pragma unroll
            for (int off = 1; off <= 8; off <<= 1) m = fmaxf(m, __shfl_xor(m, off, 64));
            float ssum = 0.f;
            #pragma unroll
            for (int j = 0; j < 8; ++j) { v[j] = expf(v[j] - m); ssum += v[j]; }
            #pragma unroll
            for (int off = 1; off <= 8; off <<= 1) ssum += __shfl_xor(ssum, off, 64);
            float inv = 1.f / ssum;
            short a8[8];
            #pragma unroll
            for (int j = 0; j < 8; ++j) a8[j] = f2bf(v[j] * inv);
            uint4 packed = make_uint4(pk2(a8[0], a8[1]), pk2(a8[2], a8[3]),
                                      pk2(a8[4], a8[5]), pk2(a8[6], a8[7]));
            *(uint4*)&Abuf[q * 136 + i0] = packed;
            *(uint4*)&Aws[((size_t)(bblk * 32 + q) * 12 + h) * 128 + i0] = packed;
        }
        __syncthreads();

        // ---- AV MFMA ----
        if (wv < 6) {
            int mt = wv & 1, nt = wv >> 1;
            f32x4 acc = 0;
            #pragma unroll
            for (int kt = 0; kt < 4; ++kt) {
                bf16x8 a = *(const bf16x8*)&Abuf[(mt * 16 + lr) * 136 + quad * 8 + kt * 32];
                BF8 bb8;
                #pragma unroll
                for (int j = 0; j < 8; ++j)
                    bb8.s[j] = vtile[(kt * 32 + quad * 8 + j) * 48 + nt * 16 + lr];
                acc = __builtin_amdgcn_mfma_f32_16x16x32_bf16(a, bb8.v, acc, 0, 0, 0);
            }
            int c = nt * 16 + lr;
            #pragma unroll
            for (int r = 0; r < 4; ++r) {
                int q = mt * 16 + quad * 4 + r;
                size_t nqg = (size_t)b * Nv + blk * BQv + q;
                if (c < 16) feats[nqg * FEAT + h * 16 + c] = acc[r];
                else if (c < 40) optraw[nqg * 288 + h * 24 + (c - 16)] = acc[r];
            }
        }
        __syncthreads();
    }
}

// ---------------- K5b: o_pair + rotation + feats ----------------
__global__ __launch_bounds__(64) void k_pair(const short* __restrict__ Aws,
                                             const short* __restrict__ pairzT,
                                             const float* __restrict__ optraw,
                                             const float* __restrict__ rots,
                                             const float* __restrict__ trans,
                                             float* __restrict__ feats) {
    __shared__ unsigned apad_u[16 * 68];
    __shared__ unsigned ppad_u[32 * 68];
    __shared__ float Rt[12];
    int t = threadIdx.x;
    int bid = blockIdx.x;          // == nqg
    int lr = t & 15, quad = t >> 4;

    if (t < 9) Rt[t] = rots[(size_t)bid * 9 + t];
    if (t < 3) Rt[9 + t] = trans[(size_t)bid * 3 + t];

    const unsigned* Asrc = (const unsigned*)(Aws + (size_t)bid * 12 * 128);
    for (int i = t; i < 768; i += 64) {
        int h = i >> 6, w32 = i & 63;
        apad_u[h * 68 + w32] = Asrc[h * 64 + w32];
    }
    for (int i = t; i < 272; i += 64) apad_u[12 * 68 + i] = 0;
    const unsigned* Psrc = (const unsigned*)(pairzT + (size_t)bid * 32 * 128);
    for (int i = t; i < 2048; i += 64) {
        int c = i >> 6, w32 = i & 63;
        ppad_u[c * 68 + w32] = Psrc[c * 64 + w32];
    }
    __syncthreads();

    const short* apad = (const short*)apad_u;
    const short* ppad = (const short*)ppad_u;
    f32x4 acc0 = 0, acc1 = 0;
    #pragma unroll
    for (int kt = 0; kt < 4; ++kt) {
        int ko = quad * 8 + kt * 32;
        bf16x8 a = *(const bf16x8*)&apad[lr * 136 + ko];
        bf16x8 b0 = *(const bf16x8*)&ppad[lr * 136 + ko];
        bf16x8 b1 = *(const bf16x8*)&ppad[(16 + lr) * 136 + ko];
        acc0 = __builtin_amdgcn_mfma_f32_16x16x32_bf16(a, b0, acc0, 0, 0, 0);
        acc1 = __builtin_amdgcn_mfma_f32_16x16x32_bf16(a, b1, acc1, 0, 0, 0);
    }
    float* frow = feats + (size_t)bid * FEAT;
    #pragma unroll
    for (int r = 0; r < 4; ++r) {
        int hh = quad * 4 + r;
        if (hh < 12) {
            frow[576 + hh * 32 + lr] = acc0[r];
            frow[576 + hh * 32 + 16 + lr] = acc1[r];
        }
    }

    for (int p = t; p < 96; p += 64) {
        float x = optraw[(size_t)bid * 288 + p * 3 + 0] - Rt[9];
        float y = optraw[(size_t)bid * 288 + p * 3 + 1] - Rt[10];
        float z = optraw[(size_t)bid * 288 + p * 3 + 2] - Rt[11];
        float lx = Rt[0] * x + Rt[3] * y + Rt[6] * z;
        float ly = Rt[1] * x + Rt[4] * y + Rt[7] * z;
        float lz = Rt[2] * x + Rt[5] * y + Rt[8] * z;
        frow[192 + p * 3 + 0] = lx;
        frow[192 + p * 3 + 1] = ly;
        frow[192 + p * 3 + 2] = lz;
        frow[480 + p] = sqrtf(lx * lx + ly * ly + lz * lz + 1e-8f);
    }
}

// ---------------- K6: out = feats @ Wout^T (4096x960x384) ----------------
__global__ __launch_bounds__(256) void k_out(const float* __restrict__ A,
                                             const float* __restrict__ Wo,
                                             float* __restrict__ C) {
    __shared__ float As[32][65];
    __shared__ float Bs[32][65];
    int t = threadIdx.x;
    int m0 = blockIdx.x * 64;
    int c0 = blockIdx.y * 64;
    int tx = t & 15, ty = t >> 4;
    int lr = t >> 2, lk = (t & 3) * 8;
    float acc[4][4] = {};
    for (int k0 = 0; k0 < FEAT; k0 += 32) {
        const float4* ap = (const float4*)(A + (size_t)(m0 + lr) * FEAT + k0 + lk);
        const float4* bp = (const float4*)(Wo + (size_t)(c0 + lr) * FEAT + k0 + lk);
        float4 a0 = ap[0], a1 = ap[1];
        float4 b0 = bp[0], b1 = bp[1];
        As[lk + 0][lr] = a0.x; As[lk + 1][lr] = a0.y; As[lk + 2][lr] = a0.z; As[lk + 3][lr] = a0.w;
        As[lk + 4][lr] = a1.x; As[lk + 5][lr] = a1.y; As[lk + 6][lr] = a1.z; As[lk + 7][lr] = a1.w;
        Bs[lk + 0][lr] = b0.x; Bs[lk + 1][lr] = b0.y; Bs[lk + 2][lr] = b0.z; Bs[lk + 3][lr] = b0.w;
        Bs[lk + 4][lr] = b1.x; Bs[lk + 5][lr] = b1.y; Bs[lk + 6][lr] = b1.z; Bs[lk + 7][lr] = b1.w;
        __syncthreads();
        #pragma unroll
        for (int kk = 0; kk < 32; ++kk) {
            float a4[4], b4[4];
            #pragma unroll
            for (int i = 0; i < 4; ++i) a4[i] = As[kk][ty * 4 + i];
            #pragma unroll
            for (int j = 0; j < 4; ++j) b4[j] = Bs[kk][tx * 4 + j];
            #pragma unroll
            for (int i = 0; i < 4; ++i)
                #pragma unroll
                for (int j = 0; j < 4; ++j) acc[i][j] += a4[i] * b4[j];
        }
        __syncthreads();
    }
    #pragma unroll
    for (int i = 0; i < 4; ++i)
        #pragma unroll
        for (int j = 0; j < 4; ++j)
            C[(size_t)(m0 + ty * 4 + i) * CSv + c0 + tx * 4 + j] = acc[i][j];
}

// ---------------- launch ----------------
extern "C" void kernel_launch(void* const* d_in, const int* in_sizes, int n_in,
                              void* d_out, int out_size, void* d_ws, size_t ws_size,
                              hipStream_t stream) {
    const float* s          = (const float*)d_in[0];
    const float* cond       = (const float*)d_in[1];
    const float* z          = (const float*)d_in[2];
    const float* trans      = (const float*)d_in[3];
    const float* rots       = (const float*)d_in[4];
    const float* smask      = (const float*)d_in[5];
    const int*   cidx       = (const int*)d_in[6];
    const float* ln_cond_w  = (const float*)d_in[7];
    const float* lin_cond_W = (const float*)d_in[8];
    const float* lin_cond_b = (const float*)d_in[9];
    const float* lin_cond_nb_W = (const float*)d_in[10];
    const float* ln_z_w     = (const float*)d_in[11];
    const float* ln_z_b     = (const float*)d_in[12];
    const float* Wq         = (const float*)d_in[13];
    const float* Wk         = (const float*)d_in[14];
    const float* Wv         = (const float*)d_in[15];
    const float* Wqp        = (const float*)d_in[16];
    const float* Wkvp       = (const float*)d_in[17];
    const float* Wb         = (const float*)d_in[18];
    const float* Wdz        = (const float*)d_in[19];
    const float* head_w     = (const float*)d_in[20];
    const float* Wout       = (const float*)d_in[21];
    float* out = (float*)d_out;

    float* p = (float*)d_ws;
    short* wp = (short*)p; p += 3072;
    float* SBp = p; p += 96;
    short* wsW  = (short*)p; p += 221184;   // 1152*384 bf16
    short* wsW2 = (short*)p; p += 98304;    // 768*256 bf16
    short* cnbf = (short*)p; p += 65536;    // 512*256 bf16
    float* gb   = p; p += (size_t)512 * 768;
    short* s2bf = (short*)p; p += (size_t)Bv * Nv * CSv / 2;
    float* proj = p; p += (size_t)Bv * Nv * PROJW;
    float* qpts = p; p += (size_t)Bv * Nv * QPD;
    float* kpts = p; p += (size_t)Bv * Nv * QPD;
    float* vpts = p; p += (size_t)Bv * Nv * (Hv * PVv * 3);
    float* qsq  = p; p += (size_t)Bv * Nv * Hv;
    float* ksq  = p; p += (size_t)Bv * Nv * Hv;
    float* bbias2 = p; p += (size_t)128 * 12 * 4096;
    short* pairzT = (short*)p; p += (size_t)128 * 32 * 32 * 64;
    short* Aws    = (short*)p; p += (size_t)4096 * 12 * 64;
    float* optraw = p; p += (size_t)4096 * 288;
    float* feats  = p; p += (size_t)Bv * Nv * FEAT;

    k_wcvt<<<624, 256, 0, stream>>>(Wq, Wk, Wv, Wqp, Wkvp, lin_cond_W, lin_cond_nb_W,
                                    wsW, wsW2);
    k_prep<<<1, 256, 0, stream>>>(Wb, Wdz, ln_z_w, ln_z_b, wp, SBp);
    k_condln<<<Bv * NCv, 256, 0, stream>>>(cond, ln_cond_w, cnbf);
    k_gemm_bt<<<dim3(4, 6), 256, 0, stream>>>(cnbf, wsW2, gb, CCONDv, 768);
    k_s2<<<Bv * Nv, 128, 0, stream>>>(s, gb, lin_cond_b, cidx, smask, s2bf);
    k_gemm_bt<<<dim3(32, 9), 256, 0, stream>>>(s2bf, wsW, proj, CSv, PROJW);
    k_post<<<Bv * Nv, 192, 0, stream>>>(proj, rots, trans, qpts, kpts, vpts, qsq, ksq);
    k_zproj2<<<Bv * NBLKv * BQv, 256, 0, stream>>>(z, wp, SBp, bbias2, pairzT);
    k_attn_main<<<Bv * NBLKv * 2, 512, 0, stream>>>(proj, qpts, kpts, vpts, qsq, ksq,
                                                    bbias2, smask, head_w, Aws, optraw, feats);
    k_pair<<<Bv * NBLKv * BQv, 64, 0, stream>>>(Aws, pairzT, optraw, rots, trans, feats);
    k_out<<<dim3(64, 6), 256, 0, stream>>>(feats, Wout, out);
}